// Round 1
// baseline (379.847 us; speedup 1.0000x reference)
//
#include <hip/hip_runtime.h>

// ---------------- problem constants ----------------
constexpr int B_  = 4;
constexpr int S_  = 2048;
constexpr int D_  = 1024;
constexpr int H_  = 16;
constexpr int DK_ = 64;
constexpr int M_  = B_ * S_;          // 8192 token rows

typedef __attribute__((ext_vector_type(8))) short short8;
typedef __attribute__((ext_vector_type(4))) float f32x4;
typedef __attribute__((ext_vector_type(4))) unsigned short us4;

__device__ __forceinline__ unsigned short f2b(float f) {
  unsigned int u = __float_as_uint(f);
  u += 0x7FFFu + ((u >> 16) & 1u);          // RNE
  return (unsigned short)(u >> 16);
}
__device__ __forceinline__ float b2f(unsigned short h) {
  return __uint_as_float(((unsigned int)h) << 16);
}

// ---------------- kernel 0: fp32 -> bf16 conversion ----------------
// xb = bf16(x) [8192x1024], wb = bf16(Wq|Wk|Wv) [3072x1024]; both live in d_out scratch.
__global__ __launch_bounds__(256) void conv_kernel(
    const float* __restrict__ x,
    const float* __restrict__ wq, const float* __restrict__ wk, const float* __restrict__ wv,
    unsigned short* __restrict__ xb, unsigned short* __restrict__ wb)
{
  const int NX4 = (M_ * D_) / 4;         // 2,097,152 float4s of x
  const int NW4 = (3 * D_ * D_) / 4;     // 786,432 float4s of W
  int stride = gridDim.x * blockDim.x;
  for (int i = blockIdx.x * blockDim.x + threadIdx.x; i < NX4 + NW4; i += stride) {
    const float4* src; unsigned short* dst; int o;
    if (i < NX4) { src = (const float4*)x; dst = xb; o = i; }
    else {
      int wi = i - NX4;
      int mat = wi >> 18;                // 262144 float4 per 1024x1024 matrix
      o = wi & 262143;
      src = (const float4*)(mat == 0 ? wq : (mat == 1 ? wk : wv));
      dst = wb + mat * (D_ * D_);
    }
    float4 v = src[o];
    us4 r; r.x = f2b(v.x); r.y = f2b(v.y); r.z = f2b(v.z); r.w = f2b(v.w);
    *(us4*)(dst + o * 4) = r;
  }
}

// ---------------- kernel 1: QKV projection GEMM (C = A * B^T) ----------------
// A = xb [8192][1024] bf16, B = wb [3072][1024] bf16.
// Epilogue scatters bf16 into q/k head-major [b][h][s][d] and v TRANSPOSED [b][h][d][s].
__global__ __launch_bounds__(256) void gemm_qkv_kernel(
    const unsigned short* __restrict__ xb,
    const unsigned short* __restrict__ wb,
    unsigned short* __restrict__ qb,
    unsigned short* __restrict__ kb,
    unsigned short* __restrict__ vtb)
{
  __shared__ unsigned short As[128][40];   // +8 pad: 2-way bank aliasing only (free)
  __shared__ unsigned short Bs[128][40];
  const int tid  = threadIdx.x;
  const int lane = tid & 63;
  const int wid  = tid >> 6;
  const int wm = wid >> 1, wn = wid & 1;
  const int m0 = blockIdx.x * 128;
  const int n0 = blockIdx.y * 128;       // global output col block (0..3071)
  const int l15 = lane & 15, l4 = lane >> 4;

  f32x4 acc[4][4] = {};

  for (int t = 0; t < 32; ++t) {         // K = 1024, BK = 32
    short8 av[2], bv[2];
    #pragma unroll
    for (int jj = 0; jj < 2; ++jj) {
      int c = tid + jj * 256;            // 512 x 16B chunks per tile
      int row = c >> 2, col = (c & 3) * 8;
      av[jj] = *(const short8*)(xb + (m0 + row) * D_ + t * 32 + col);
      bv[jj] = *(const short8*)(wb + (n0 + row) * D_ + t * 32 + col);
    }
    __syncthreads();
    #pragma unroll
    for (int jj = 0; jj < 2; ++jj) {
      int c = tid + jj * 256;
      int row = c >> 2, col = (c & 3) * 8;
      *(short8*)&As[row][col] = av[jj];
      *(short8*)&Bs[row][col] = bv[jj];
    }
    __syncthreads();
    short8 af[4], bfr[4];
    #pragma unroll
    for (int mi = 0; mi < 4; ++mi) af[mi]  = *(const short8*)&As[wm*64 + mi*16 + l15][l4*8];
    #pragma unroll
    for (int ni = 0; ni < 4; ++ni) bfr[ni] = *(const short8*)&Bs[wn*64 + ni*16 + l15][l4*8];
    #pragma unroll
    for (int mi = 0; mi < 4; ++mi)
      #pragma unroll
      for (int ni = 0; ni < 4; ++ni)
        acc[mi][ni] = __builtin_amdgcn_mfma_f32_16x16x32_bf16(af[mi], bfr[ni], acc[mi][ni], 0, 0, 0);
  }

  #pragma unroll
  for (int mi = 0; mi < 4; ++mi)
    #pragma unroll
    for (int ni = 0; ni < 4; ++ni)
      #pragma unroll
      for (int j = 0; j < 4; ++j) {
        int row = m0 + wm*64 + mi*16 + l4*4 + j;   // token m
        int col = n0 + wn*64 + ni*16 + l15;        // 0..3071
        unsigned short u = f2b(acc[mi][ni][j]);
        int bidx = row >> 11, s = row & 2047;
        int mat = col >> 10, oo = col & 1023;
        int h = oo >> 6, dd = oo & 63;
        if (mat == 0)      qb[((bidx*H_ + h)*S_ + s)*DK_ + dd] = u;
        else if (mat == 1) kb[((bidx*H_ + h)*S_ + s)*DK_ + dd] = u;
        else               vtb[((bidx*H_ + h)*DK_ + dd)*S_ + s] = u;
      }
}

// ---------------- kernel 2: RoPE in place on q and k ----------------
__global__ __launch_bounds__(256) void rope_kernel(
    unsigned short* __restrict__ qb, unsigned short* __restrict__ kb,
    const float* __restrict__ cs, const int* __restrict__ pos)
{
  int i = blockIdx.x * 256 + threadIdx.x;        // pair index, 8,388,608 total
  const int PT = B_ * H_ * S_ * 32;              // pairs per tensor
  unsigned short* buf = (i < PT) ? qb : kb;
  int idx = (i < PT) ? i : i - PT;
  int kk = idx & 31; idx >>= 5;
  int s  = idx & 2047; idx >>= 11;
  int bh = idx;                                  // b*16+h
  int p = pos[s];
  float c  = cs[(p*32 + kk)*2 + 0];
  float sn = cs[(p*32 + kk)*2 + 1];
  int addr = (bh*S_ + s)*DK_ + kk*2;
  unsigned int word = *(unsigned int*)(buf + addr);
  float x0 = b2f((unsigned short)(word & 0xFFFFu));
  float x1 = b2f((unsigned short)(word >> 16));
  float r0 = c*x0 - sn*x1;
  float r1 = sn*x0 + c*x1;
  *(unsigned int*)(buf + addr) = (unsigned int)f2b(r0) | ((unsigned int)f2b(r1) << 16);
}

// ---------------- kernel 3: causal flash attention ----------------
// grid (S/64, B*H); 4 waves, each wave owns 16 q-rows; K-tile = 64 keys.
__global__ __launch_bounds__(256) void attn_kernel(
    const unsigned short* __restrict__ qb,
    const unsigned short* __restrict__ kb,
    const unsigned short* __restrict__ vtb,
    unsigned short* __restrict__ ao)
{
  __shared__ unsigned short Ks[64][72];      // [key][dim], pad 72 -> conflict-free b128 frags
  __shared__ unsigned short Vs[64][72];      // [dim][key] (v stored pre-transposed globally)
  __shared__ unsigned short Ps[4][16][72];   // wave-private P relayout C->A
  const int tid = threadIdx.x, lane = tid & 63, wid = tid >> 6;
  const int l15 = lane & 15, l4 = lane >> 4;
  const int bh = blockIdx.y;
  const int q0 = blockIdx.x * 64;
  const unsigned short* qp = qb  + bh * S_ * DK_;
  const unsigned short* kp = kb  + bh * S_ * DK_;
  const unsigned short* vp = vtb + bh * DK_ * S_;

  short8 qf[2];                              // Q A-fragments (row = l15, dims l4*8 + 32*kb)
  #pragma unroll
  for (int kbk = 0; kbk < 2; ++kbk)
    qf[kbk] = *(const short8*)(qp + (q0 + wid*16 + l15)*DK_ + kbk*32 + l4*8);

  f32x4 oacc[4] = {};
  float mrun[4], lrun[4];
  #pragma unroll
  for (int j = 0; j < 4; ++j) { mrun[j] = -1e30f; lrun[j] = 0.0f; }

  const int nkt = blockIdx.x + 1;            // causal: only tiles with keys <= q0+63
  for (int kt = 0; kt < nkt; ++kt) {
    short8 kv[2], vv[2];
    #pragma unroll
    for (int jj = 0; jj < 2; ++jj) {
      int c = tid + jj * 256;
      int r = c >> 3, col = (c & 7) * 8;
      kv[jj] = *(const short8*)(kp + (kt*64 + r)*DK_ + col);
      vv[jj] = *(const short8*)(vp + r*S_ + kt*64 + col);
    }
    __syncthreads();
    #pragma unroll
    for (int jj = 0; jj < 2; ++jj) {
      int c = tid + jj * 256;
      int r = c >> 3, col = (c & 7) * 8;
      *(short8*)&Ks[r][col] = kv[jj];
      *(short8*)&Vs[r][col] = vv[jj];
    }
    __syncthreads();

    // scores: S = Q * K^T (per wave: 16 rows x 64 keys)
    f32x4 sc[4];
    #pragma unroll
    for (int nb = 0; nb < 4; ++nb) {
      short8 k0 = *(const short8*)&Ks[nb*16 + l15][l4*8];
      short8 k1 = *(const short8*)&Ks[nb*16 + l15][32 + l4*8];
      f32x4 z = {};
      z = __builtin_amdgcn_mfma_f32_16x16x32_bf16(qf[0], k0, z, 0, 0, 0);
      z = __builtin_amdgcn_mfma_f32_16x16x32_bf16(qf[1], k1, z, 0, 0, 0);
      sc[nb] = z;
    }

    const int rbase = q0 + wid*16 + l4*4;
    if (kt == nkt - 1) {                     // only the diagonal tile needs the mask
      #pragma unroll
      for (int nb = 0; nb < 4; ++nb) {
        int key = kt*64 + nb*16 + l15;
        #pragma unroll
        for (int j = 0; j < 4; ++j) {
          float sv = sc[nb][j] * 0.125f;
          sc[nb][j] = (key > rbase + j) ? -1e30f : sv;
        }
      }
    } else {
      #pragma unroll
      for (int nb = 0; nb < 4; ++nb)
        #pragma unroll
        for (int j = 0; j < 4; ++j)
          sc[nb][j] *= 0.125f;
    }

    // online softmax; rows live in 16-lane groups (same l4), butterfly over masks 1,2,4,8
    #pragma unroll
    for (int j = 0; j < 4; ++j) {
      float tm = fmaxf(fmaxf(sc[0][j], sc[1][j]), fmaxf(sc[2][j], sc[3][j]));
      tm = fmaxf(tm, __shfl_xor(tm, 1));
      tm = fmaxf(tm, __shfl_xor(tm, 2));
      tm = fmaxf(tm, __shfl_xor(tm, 4));
      tm = fmaxf(tm, __shfl_xor(tm, 8));
      float mnew = fmaxf(mrun[j], tm);
      float corr = __expf(mrun[j] - mnew);
      mrun[j] = mnew;
      float rs = 0.0f;
      #pragma unroll
      for (int nb = 0; nb < 4; ++nb) {
        float p = __expf(sc[nb][j] - mnew);
        sc[nb][j] = p;
        rs += p;
      }
      rs += __shfl_xor(rs, 1); rs += __shfl_xor(rs, 2);
      rs += __shfl_xor(rs, 4); rs += __shfl_xor(rs, 8);
      lrun[j] = lrun[j] * corr + rs;
      #pragma unroll
      for (int nb = 0; nb < 4; ++nb) oacc[nb][j] *= corr;
    }

    // P: C-layout -> A-layout via wave-private LDS (same-wave DS ops are in-order)
    #pragma unroll
    for (int nb = 0; nb < 4; ++nb)
      #pragma unroll
      for (int j = 0; j < 4; ++j)
        Ps[wid][l4*4 + j][nb*16 + l15] = f2b(sc[nb][j]);
    asm volatile("s_waitcnt lgkmcnt(0)" ::: "memory");

    short8 pa[2];
    #pragma unroll
    for (int kbk = 0; kbk < 2; ++kbk)
      pa[kbk] = *(const short8*)&Ps[wid][l15][kbk*32 + l4*8];

    // O += P * V   (B-frag: col = dim = nb*16+l15, k = keys l4*8 + 32*kb)
    #pragma unroll
    for (int nb = 0; nb < 4; ++nb) {
      short8 v0 = *(const short8*)&Vs[nb*16 + l15][l4*8];
      short8 v1 = *(const short8*)&Vs[nb*16 + l15][32 + l4*8];
      oacc[nb] = __builtin_amdgcn_mfma_f32_16x16x32_bf16(pa[0], v0, oacc[nb], 0, 0, 0);
      oacc[nb] = __builtin_amdgcn_mfma_f32_16x16x32_bf16(pa[1], v1, oacc[nb], 0, 0, 0);
    }
  }

  const int bidx = bh >> 4, h = bh & 15;
  #pragma unroll
  for (int nb = 0; nb < 4; ++nb)
    #pragma unroll
    for (int j = 0; j < 4; ++j) {
      int srow = q0 + wid*16 + l4*4 + j;
      int dim = nb*16 + l15;
      float val = oacc[nb][j] / lrun[j];
      ao[((bidx*S_ + srow)*H_ + h)*DK_ + dim] = f2b(val);   // [b][s][h][d] = [m][1024]
    }
}

// ---------------- kernel 4: output projection (C = A * Wo^T), fp32 out ----------------
__global__ __launch_bounds__(256) void gemm_out_kernel(
    const unsigned short* __restrict__ ao,   // [8192][1024] bf16
    const float* __restrict__ wo,            // [1024][1024] fp32 (converted during staging)
    float* __restrict__ out)                 // [8192][1024] fp32
{
  __shared__ unsigned short As[128][40];
  __shared__ unsigned short Bs[128][40];
  const int tid = threadIdx.x, lane = tid & 63, wid = tid >> 6;
  const int wm = wid >> 1, wn = wid & 1;
  const int m0 = blockIdx.x * 128, n0 = blockIdx.y * 128;
  const int l15 = lane & 15, l4 = lane >> 4;

  f32x4 acc[4][4] = {};

  for (int t = 0; t < 32; ++t) {
    short8 av[2];
    float4 bw[4];
    #pragma unroll
    for (int jj = 0; jj < 2; ++jj) {
      int c = tid + jj * 256;
      int row = c >> 2, col = (c & 3) * 8;
      av[jj] = *(const short8*)(ao + (m0 + row) * D_ + t * 32 + col);
    }
    #pragma unroll
    for (int jj = 0; jj < 4; ++jj) {
      int c = tid + jj * 256;
      int row = c >> 3, col = (c & 7) * 4;
      bw[jj] = *(const float4*)(wo + (n0 + row) * D_ + t * 32 + col);
    }
    __syncthreads();
    #pragma unroll
    for (int jj = 0; jj < 2; ++jj) {
      int c = tid + jj * 256;
      int row = c >> 2, col = (c & 3) * 8;
      *(short8*)&As[row][col] = av[jj];
    }
    #pragma unroll
    for (int jj = 0; jj < 4; ++jj) {
      int c = tid + jj * 256;
      int row = c >> 3, col = (c & 7) * 4;
      us4 r; r.x = f2b(bw[jj].x); r.y = f2b(bw[jj].y); r.z = f2b(bw[jj].z); r.w = f2b(bw[jj].w);
      *(us4*)&Bs[row][col] = r;
    }
    __syncthreads();
    short8 af[4], bfr[4];
    #pragma unroll
    for (int mi = 0; mi < 4; ++mi) af[mi]  = *(const short8*)&As[wm*64 + mi*16 + l15][l4*8];
    #pragma unroll
    for (int ni = 0; ni < 4; ++ni) bfr[ni] = *(const short8*)&Bs[wn*64 + ni*16 + l15][l4*8];
    #pragma unroll
    for (int mi = 0; mi < 4; ++mi)
      #pragma unroll
      for (int ni = 0; ni < 4; ++ni)
        acc[mi][ni] = __builtin_amdgcn_mfma_f32_16x16x32_bf16(af[mi], bfr[ni], acc[mi][ni], 0, 0, 0);
  }

  #pragma unroll
  for (int mi = 0; mi < 4; ++mi)
    #pragma unroll
    for (int ni = 0; ni < 4; ++ni)
      #pragma unroll
      for (int j = 0; j < 4; ++j) {
        int row = m0 + wm*64 + mi*16 + l4*4 + j;
        int col = n0 + wn*64 + ni*16 + l15;
        out[row * D_ + col] = acc[mi][ni][j];
      }
}

// ---------------- launcher ----------------
extern "C" void kernel_launch(void* const* d_in, const int* in_sizes, int n_in,
                              void* d_out, int out_size, void* d_ws, size_t ws_size,
                              hipStream_t stream)
{
  const float* x  = (const float*)d_in[0];
  const float* wq = (const float*)d_in[1];
  const float* wk = (const float*)d_in[2];
  const float* wv = (const float*)d_in[3];
  const float* wo = (const float*)d_in[4];
  const float* cs = (const float*)d_in[5];
  const int*  pos = (const int*)d_in[6];
  float* out = (float*)d_out;

  // d_out doubles as scratch for the bf16 copies of x and Wq|Wk|Wv (23.1 MB < 32 MB);
  // it is fully overwritten by gemm_out_kernel at the end.
  unsigned short* xb = (unsigned short*)d_out;
  unsigned short* wb = xb + M_ * D_;

  // d_ws: q | k | v^T | attn_out, bf16, 16 MiB each = 64 MiB total
  unsigned short* qb  = (unsigned short*)d_ws;
  unsigned short* kbf = qb  + M_ * D_;
  unsigned short* vtb = kbf + M_ * D_;
  unsigned short* aob = vtb + M_ * D_;

  conv_kernel<<<dim3(2048), dim3(256), 0, stream>>>(x, wq, wk, wv, xb, wb);
  gemm_qkv_kernel<<<dim3(64, 24), dim3(256), 0, stream>>>(xb, wb, qb, kbf, vtb);
  rope_kernel<<<dim3(32768), dim3(256), 0, stream>>>(qb, kbf, cs, pos);
  attn_kernel<<<dim3(32, 64), dim3(256), 0, stream>>>(qb, kbf, vtb, aob);
  gemm_out_kernel<<<dim3(64, 8), dim3(256), 0, stream>>>(aob, wo, out);

  (void)in_sizes; (void)n_in; (void)out_size; (void)ws_size;
}

// Round 2
// 248.384 us; speedup vs baseline: 1.5293x; 1.5293x over previous
//
#include <hip/hip_runtime.h>

// ---------------- problem constants ----------------
constexpr int B_  = 4;
constexpr int S_  = 2048;
constexpr int D_  = 1024;
constexpr int H_  = 16;
constexpr int DK_ = 64;
constexpr int M_  = B_ * S_;          // 8192 token rows

typedef __attribute__((ext_vector_type(8))) short short8;
typedef __attribute__((ext_vector_type(4))) float f32x4;
typedef __attribute__((ext_vector_type(4))) unsigned short us4;

__device__ __forceinline__ unsigned short f2b(float f) {
  unsigned int u = __float_as_uint(f);
  u += 0x7FFFu + ((u >> 16) & 1u);          // RNE
  return (unsigned short)(u >> 16);
}
__device__ __forceinline__ float b2f(unsigned short h) {
  return __uint_as_float(((unsigned int)h) << 16);
}

// ---------------- kernel 0: fp32 -> bf16 conversion ----------------
__global__ __launch_bounds__(256) void conv_kernel(
    const float* __restrict__ x,
    const float* __restrict__ wq, const float* __restrict__ wk, const float* __restrict__ wv,
    unsigned short* __restrict__ xb, unsigned short* __restrict__ wb)
{
  const int NX4 = (M_ * D_) / 4;
  const int NW4 = (3 * D_ * D_) / 4;
  int stride = gridDim.x * blockDim.x;
  for (int i = blockIdx.x * blockDim.x + threadIdx.x; i < NX4 + NW4; i += stride) {
    const float4* src; unsigned short* dst; int o;
    if (i < NX4) { src = (const float4*)x; dst = xb; o = i; }
    else {
      int wi = i - NX4;
      int mat = wi >> 18;
      o = wi & 262143;
      src = (const float4*)(mat == 0 ? wq : (mat == 1 ? wk : wv));
      dst = wb + mat * (D_ * D_);
    }
    float4 v = src[o];
    us4 r; r.x = f2b(v.x); r.y = f2b(v.y); r.z = f2b(v.z); r.w = f2b(v.w);
    *(us4*)(dst + o * 4) = r;
  }
}

// ---------------- kernel 1: QKV projection GEMM (C = A * B^T) ----------------
__global__ __launch_bounds__(256) void gemm_qkv_kernel(
    const unsigned short* __restrict__ xb,
    const unsigned short* __restrict__ wb,
    unsigned short* __restrict__ qb,
    unsigned short* __restrict__ kb,
    unsigned short* __restrict__ vtb)
{
  __shared__ unsigned short As[128][40];
  __shared__ unsigned short Bs[128][40];
  const int tid  = threadIdx.x;
  const int lane = tid & 63;
  const int wid  = tid >> 6;
  const int wm = wid >> 1, wn = wid & 1;
  const int m0 = blockIdx.x * 128;
  const int n0 = blockIdx.y * 128;
  const int l15 = lane & 15, l4 = lane >> 4;

  f32x4 acc[4][4] = {};

  for (int t = 0; t < 32; ++t) {
    short8 av[2], bv[2];
    #pragma unroll
    for (int jj = 0; jj < 2; ++jj) {
      int c = tid + jj * 256;
      int row = c >> 2, col = (c & 3) * 8;
      av[jj] = *(const short8*)(xb + (m0 + row) * D_ + t * 32 + col);
      bv[jj] = *(const short8*)(wb + (n0 + row) * D_ + t * 32 + col);
    }
    __syncthreads();
    #pragma unroll
    for (int jj = 0; jj < 2; ++jj) {
      int c = tid + jj * 256;
      int row = c >> 2, col = (c & 3) * 8;
      *(short8*)&As[row][col] = av[jj];
      *(short8*)&Bs[row][col] = bv[jj];
    }
    __syncthreads();
    short8 af[4], bfr[4];
    #pragma unroll
    for (int mi = 0; mi < 4; ++mi) af[mi]  = *(const short8*)&As[wm*64 + mi*16 + l15][l4*8];
    #pragma unroll
    for (int ni = 0; ni < 4; ++ni) bfr[ni] = *(const short8*)&Bs[wn*64 + ni*16 + l15][l4*8];
    #pragma unroll
    for (int mi = 0; mi < 4; ++mi)
      #pragma unroll
      for (int ni = 0; ni < 4; ++ni)
        acc[mi][ni] = __builtin_amdgcn_mfma_f32_16x16x32_bf16(af[mi], bfr[ni], acc[mi][ni], 0, 0, 0);
  }

  #pragma unroll
  for (int mi = 0; mi < 4; ++mi)
    #pragma unroll
    for (int ni = 0; ni < 4; ++ni)
      #pragma unroll
      for (int j = 0; j < 4; ++j) {
        int row = m0 + wm*64 + mi*16 + l4*4 + j;
        int col = n0 + wn*64 + ni*16 + l15;
        unsigned short u = f2b(acc[mi][ni][j]);
        int bidx = row >> 11, s = row & 2047;
        int mat = col >> 10, oo = col & 1023;
        int h = oo >> 6, dd = oo & 63;
        if (mat == 0)      qb[((bidx*H_ + h)*S_ + s)*DK_ + dd] = u;
        else if (mat == 1) kb[((bidx*H_ + h)*S_ + s)*DK_ + dd] = u;
        else               vtb[((bidx*H_ + h)*DK_ + dd)*S_ + s] = u;
      }
}

// ---------------- kernel 2: RoPE in place on q and k ----------------
__global__ __launch_bounds__(256) void rope_kernel(
    unsigned short* __restrict__ qb, unsigned short* __restrict__ kb,
    const float* __restrict__ cs, const int* __restrict__ pos)
{
  int i = blockIdx.x * 256 + threadIdx.x;
  const int PT = B_ * H_ * S_ * 32;
  unsigned short* buf = (i < PT) ? qb : kb;
  int idx = (i < PT) ? i : i - PT;
  int kk = idx & 31; idx >>= 5;
  int s  = idx & 2047; idx >>= 11;
  int bh = idx;
  int p = pos[s];
  float c  = cs[(p*32 + kk)*2 + 0];
  float sn = cs[(p*32 + kk)*2 + 1];
  int addr = (bh*S_ + s)*DK_ + kk*2;
  unsigned int word = *(unsigned int*)(buf + addr);
  float x0 = b2f((unsigned short)(word & 0xFFFFu));
  float x1 = b2f((unsigned short)(word >> 16));
  float r0 = c*x0 - sn*x1;
  float r1 = sn*x0 + c*x1;
  *(unsigned int*)(buf + addr) = (unsigned int)f2b(r0) | ((unsigned int)f2b(r1) << 16);
}

// ---------------- kernel 3: causal flash attention v2 ----------------
// grid (16, B*H). Each block processes q-tiles bx and 31-bx (perfect balance: 33 stagings).
// Swapped QK^T: sc = mfma(K, Q) -> C col = q-row (l15), row = key (l4*4+j).
// Each lane owns ONE q-row, 16 keys in-register -> softmax is in-lane + 2 shfl_xor.
__global__ __launch_bounds__(256, 4) void attn_kernel(
    const unsigned short* __restrict__ qb,
    const unsigned short* __restrict__ kb,
    const unsigned short* __restrict__ vtb,
    unsigned short* __restrict__ ao)
{
  __shared__ unsigned short Ks[64][72];      // [key][dim]
  __shared__ unsigned short Vs[64][72];      // [dim][key]
  __shared__ unsigned short Ps[4][16][72];   // wave-private P: [qrow][key]
  const int tid = threadIdx.x, lane = tid & 63, wid = tid >> 6;
  const int l15 = lane & 15, l4 = lane >> 4;
  const int bh = blockIdx.y;
  const unsigned short* qp = qb  + bh * S_ * DK_;
  const unsigned short* kp = kb  + bh * S_ * DK_;
  const unsigned short* vp = vtb + bh * DK_ * S_;
  const int bidx = bh >> 4, h = bh & 15;

  for (int half = 0; half < 2; ++half) {
    const int qt = half ? (31 - (int)blockIdx.x) : (int)blockIdx.x;
    const int q0 = qt * 64;
    const int nkt = qt + 1;

    // Q B-frags (rows = q-rows = l15), pre-scaled by 1/sqrt(d) = 2^-3 (exact in bf16)
    short8 qf[2];
    #pragma unroll
    for (int kbk = 0; kbk < 2; ++kbk) {
      short8 raw = *(const short8*)(qp + (q0 + wid*16 + l15)*DK_ + kbk*32 + l4*8);
      #pragma unroll
      for (int i = 0; i < 8; ++i) {
        float f = b2f((unsigned short)raw[i]) * 0.125f;
        raw[i] = (short)f2b(f);
      }
      qf[kbk] = raw;
    }

    f32x4 oacc[4] = {};
    float mrun = -1e30f, lrun = 0.0f;

    short8 kv[2], vv[2];
    // prologue: issue loads for kt = 0
    #pragma unroll
    for (int jj = 0; jj < 2; ++jj) {
      int c = tid + jj * 256;
      int r = c >> 3, col = (c & 7) * 8;
      kv[jj] = *(const short8*)(kp + r*DK_ + col);
      vv[jj] = *(const short8*)(vp + r*S_ + col);
    }

    for (int kt = 0; kt < nkt; ++kt) {
      __syncthreads();                       // prior tile's readers done
      #pragma unroll
      for (int jj = 0; jj < 2; ++jj) {
        int c = tid + jj * 256;
        int r = c >> 3, col = (c & 7) * 8;
        *(short8*)&Ks[r][col] = kv[jj];
        *(short8*)&Vs[r][col] = vv[jj];
      }
      __syncthreads();                       // tile ready

      if (kt + 1 < nkt) {                    // T14: prefetch next tile under compute
        #pragma unroll
        for (int jj = 0; jj < 2; ++jj) {
          int c = tid + jj * 256;
          int r = c >> 3, col = (c & 7) * 8;
          kv[jj] = *(const short8*)(kp + ((kt+1)*64 + r)*DK_ + col);
          vv[jj] = *(const short8*)(vp + r*S_ + (kt+1)*64 + col);
        }
      }

      // swapped QK^T: A = K rows (keys), B = Q rows (q-rows)
      f32x4 sc[4];
      __builtin_amdgcn_s_setprio(1);
      #pragma unroll
      for (int nb = 0; nb < 4; ++nb) {
        short8 k0 = *(const short8*)&Ks[nb*16 + l15][l4*8];
        short8 k1 = *(const short8*)&Ks[nb*16 + l15][32 + l4*8];
        f32x4 z = {};
        z = __builtin_amdgcn_mfma_f32_16x16x32_bf16(k0, qf[0], z, 0, 0, 0);
        z = __builtin_amdgcn_mfma_f32_16x16x32_bf16(k1, qf[1], z, 0, 0, 0);
        sc[nb] = z;
      }
      __builtin_amdgcn_s_setprio(0);

      if (kt == nkt - 1) {                   // diagonal tile mask
        const int qg = q0 + wid*16 + l15;
        #pragma unroll
        for (int nb = 0; nb < 4; ++nb)
          #pragma unroll
          for (int j = 0; j < 4; ++j) {
            int kg = kt*64 + nb*16 + l4*4 + j;
            if (kg > qg) sc[nb][j] = -1e30f;
          }
      }

      // softmax: row = l15, keys in-register (16) + group of 4 lanes (xor 16, 32)
      float tm = sc[0][0];
      #pragma unroll
      for (int nb = 0; nb < 4; ++nb)
        #pragma unroll
        for (int j = 0; j < 4; ++j) tm = fmaxf(tm, sc[nb][j]);
      tm = fmaxf(tm, __shfl_xor(tm, 16));
      tm = fmaxf(tm, __shfl_xor(tm, 32));
      float mnew = fmaxf(mrun, tm);
      float corr = __expf(mrun - mnew);
      mrun = mnew;
      float rs = 0.0f;
      #pragma unroll
      for (int nb = 0; nb < 4; ++nb)
        #pragma unroll
        for (int j = 0; j < 4; ++j) {
          float p = __expf(sc[nb][j] - mnew);
          sc[nb][j] = p;
          rs += p;
        }
      rs += __shfl_xor(rs, 16);
      rs += __shfl_xor(rs, 32);
      lrun = lrun * corr + rs;

      // rescale oacc: its rows are q-rows l4*4+j; fetch that row's corr from lane l4*4+j
      #pragma unroll
      for (int j = 0; j < 4; ++j) {
        float cj = __shfl(corr, l4*4 + j);
        #pragma unroll
        for (int nb = 0; nb < 4; ++nb) oacc[nb][j] *= cj;
      }

      // P -> Ps (vector b64, 2-way bank alias = free), then read back as A-frags
      #pragma unroll
      for (int nb = 0; nb < 4; ++nb) {
        uint2 w;
        w.x = (unsigned int)f2b(sc[nb][0]) | ((unsigned int)f2b(sc[nb][1]) << 16);
        w.y = (unsigned int)f2b(sc[nb][2]) | ((unsigned int)f2b(sc[nb][3]) << 16);
        *(uint2*)&Ps[wid][l15][nb*16 + l4*4] = w;
      }
      asm volatile("s_waitcnt lgkmcnt(0)" ::: "memory");
      short8 pa0 = *(const short8*)&Ps[wid][l15][l4*8];
      short8 pa1 = *(const short8*)&Ps[wid][l15][32 + l4*8];

      // O += P * V
      __builtin_amdgcn_s_setprio(1);
      #pragma unroll
      for (int nb = 0; nb < 4; ++nb) {
        short8 v0 = *(const short8*)&Vs[nb*16 + l15][l4*8];
        short8 v1 = *(const short8*)&Vs[nb*16 + l15][32 + l4*8];
        oacc[nb] = __builtin_amdgcn_mfma_f32_16x16x32_bf16(pa0, v0, oacc[nb], 0, 0, 0);
        oacc[nb] = __builtin_amdgcn_mfma_f32_16x16x32_bf16(pa1, v1, oacc[nb], 0, 0, 0);
      }
      __builtin_amdgcn_s_setprio(0);
    }

    // epilogue: oacc rows = q-rows l4*4+j; lrun lives at lane l4*4+j
    #pragma unroll
    for (int j = 0; j < 4; ++j) {
      float lj = __shfl(lrun, l4*4 + j);
      float inv = 1.0f / lj;
      int row = q0 + wid*16 + l4*4 + j;
      #pragma unroll
      for (int nb = 0; nb < 4; ++nb) {
        int dim = nb*16 + l15;
        ao[((bidx*S_ + row)*H_ + h)*DK_ + dim] = f2b(oacc[nb][j] * inv);
      }
    }
  }
}

// ---------------- kernel 4: output projection (C = A * Wo^T), fp32 out ----------------
__global__ __launch_bounds__(256) void gemm_out_kernel(
    const unsigned short* __restrict__ ao,
    const float* __restrict__ wo,
    float* __restrict__ out)
{
  __shared__ unsigned short As[128][40];
  __shared__ unsigned short Bs[128][40];
  const int tid = threadIdx.x, lane = tid & 63, wid = tid >> 6;
  const int wm = wid >> 1, wn = wid & 1;
  const int m0 = blockIdx.x * 128, n0 = blockIdx.y * 128;
  const int l15 = lane & 15, l4 = lane >> 4;

  f32x4 acc[4][4] = {};

  for (int t = 0; t < 32; ++t) {
    short8 av[2];
    float4 bw[4];
    #pragma unroll
    for (int jj = 0; jj < 2; ++jj) {
      int c = tid + jj * 256;
      int row = c >> 2, col = (c & 3) * 8;
      av[jj] = *(const short8*)(ao + (m0 + row) * D_ + t * 32 + col);
    }
    #pragma unroll
    for (int jj = 0; jj < 4; ++jj) {
      int c = tid + jj * 256;
      int row = c >> 3, col = (c & 7) * 4;
      bw[jj] = *(const float4*)(wo + (n0 + row) * D_ + t * 32 + col);
    }
    __syncthreads();
    #pragma unroll
    for (int jj = 0; jj < 2; ++jj) {
      int c = tid + jj * 256;
      int row = c >> 2, col = (c & 3) * 8;
      *(short8*)&As[row][col] = av[jj];
    }
    #pragma unroll
    for (int jj = 0; jj < 4; ++jj) {
      int c = tid + jj * 256;
      int row = c >> 3, col = (c & 7) * 4;
      us4 r; r.x = f2b(bw[jj].x); r.y = f2b(bw[jj].y); r.z = f2b(bw[jj].z); r.w = f2b(bw[jj].w);
      *(us4*)&Bs[row][col] = r;
    }
    __syncthreads();
    short8 af[4], bfr[4];
    #pragma unroll
    for (int mi = 0; mi < 4; ++mi) af[mi]  = *(const short8*)&As[wm*64 + mi*16 + l15][l4*8];
    #pragma unroll
    for (int ni = 0; ni < 4; ++ni) bfr[ni] = *(const short8*)&Bs[wn*64 + ni*16 + l15][l4*8];
    #pragma unroll
    for (int mi = 0; mi < 4; ++mi)
      #pragma unroll
      for (int ni = 0; ni < 4; ++ni)
        acc[mi][ni] = __builtin_amdgcn_mfma_f32_16x16x32_bf16(af[mi], bfr[ni], acc[mi][ni], 0, 0, 0);
  }

  #pragma unroll
  for (int mi = 0; mi < 4; ++mi)
    #pragma unroll
    for (int ni = 0; ni < 4; ++ni)
      #pragma unroll
      for (int j = 0; j < 4; ++j) {
        int row = m0 + wm*64 + mi*16 + l4*4 + j;
        int col = n0 + wn*64 + ni*16 + l15;
        out[row * D_ + col] = acc[mi][ni][j];
      }
}

// ---------------- launcher ----------------
extern "C" void kernel_launch(void* const* d_in, const int* in_sizes, int n_in,
                              void* d_out, int out_size, void* d_ws, size_t ws_size,
                              hipStream_t stream)
{
  const float* x  = (const float*)d_in[0];
  const float* wq = (const float*)d_in[1];
  const float* wk = (const float*)d_in[2];
  const float* wv = (const float*)d_in[3];
  const float* wo = (const float*)d_in[4];
  const float* cs = (const float*)d_in[5];
  const int*  pos = (const int*)d_in[6];
  float* out = (float*)d_out;

  unsigned short* xb = (unsigned short*)d_out;   // d_out as scratch until final GEMM
  unsigned short* wb = xb + M_ * D_;

  unsigned short* qb  = (unsigned short*)d_ws;
  unsigned short* kbf = qb  + M_ * D_;
  unsigned short* vtb = kbf + M_ * D_;
  unsigned short* aob = vtb + M_ * D_;

  conv_kernel<<<dim3(2048), dim3(256), 0, stream>>>(x, wq, wk, wv, xb, wb);
  gemm_qkv_kernel<<<dim3(64, 24), dim3(256), 0, stream>>>(xb, wb, qb, kbf, vtb);
  rope_kernel<<<dim3(32768), dim3(256), 0, stream>>>(qb, kbf, cs, pos);
  attn_kernel<<<dim3(16, 64), dim3(256), 0, stream>>>(qb, kbf, vtb, aob);
  gemm_out_kernel<<<dim3(64, 8), dim3(256), 0, stream>>>(aob, wo, out);

  (void)in_sizes; (void)n_in; (void)out_size; (void)ws_size;
}

// Round 3
// 216.386 us; speedup vs baseline: 1.7554x; 1.1479x over previous
//
#include <hip/hip_runtime.h>

// ---------------- problem constants ----------------
constexpr int B_  = 4;
constexpr int S_  = 2048;
constexpr int D_  = 1024;
constexpr int H_  = 16;
constexpr int DK_ = 64;
constexpr int M_  = B_ * S_;          // 8192 token rows

typedef __attribute__((ext_vector_type(8))) short short8;
typedef __attribute__((ext_vector_type(4))) float f32x4;
typedef __attribute__((ext_vector_type(4))) unsigned short us4;

__device__ __forceinline__ unsigned short f2b(float f) {
  unsigned int u = __float_as_uint(f);
  u += 0x7FFFu + ((u >> 16) & 1u);          // RNE
  return (unsigned short)(u >> 16);
}
__device__ __forceinline__ float b2f(unsigned short h) {
  return __uint_as_float(((unsigned int)h) << 16);
}

// async global->LDS, 16B per lane; LDS dest must be wave-uniform base (+ lane*16 by HW)
#define GLOAD16(g, l) __builtin_amdgcn_global_load_lds( \
    (const __attribute__((address_space(1))) unsigned int*)(g), \
    (__attribute__((address_space(3))) unsigned int*)(l), 16, 0, 0)

// ---------------- kernel 0: fp32 -> bf16 conversion (x, Wq|Wk|Wv) ----------------
__global__ __launch_bounds__(256) void conv_kernel(
    const float* __restrict__ x,
    const float* __restrict__ wq, const float* __restrict__ wk, const float* __restrict__ wv,
    unsigned short* __restrict__ xb, unsigned short* __restrict__ wb)
{
  const int NX4 = (M_ * D_) / 4;
  const int NW4 = (3 * D_ * D_) / 4;
  int stride = gridDim.x * blockDim.x;
  for (int i = blockIdx.x * blockDim.x + threadIdx.x; i < NX4 + NW4; i += stride) {
    const float4* src; unsigned short* dst; int o;
    if (i < NX4) { src = (const float4*)x; dst = xb; o = i; }
    else {
      int wi = i - NX4;
      int mat = wi >> 18;
      o = wi & 262143;
      src = (const float4*)(mat == 0 ? wq : (mat == 1 ? wk : wv));
      dst = wb + mat * (D_ * D_);
    }
    float4 v = src[o];
    us4 r; r.x = f2b(v.x); r.y = f2b(v.y); r.z = f2b(v.z); r.w = f2b(v.w);
    *(us4*)(dst + o * 4) = r;
  }
}

// ---------------- kernel 0b: Wo fp32 -> bf16 (runs after attn; wob in dead q region) ----
__global__ __launch_bounds__(256) void conv_wo_kernel(
    const float* __restrict__ wo, unsigned short* __restrict__ wob)
{
  int i = blockIdx.x * 256 + threadIdx.x;       // 262144 float4s
  float4 v = ((const float4*)wo)[i];
  us4 r; r.x = f2b(v.x); r.y = f2b(v.y); r.z = f2b(v.z); r.w = f2b(v.w);
  *(us4*)(wob + i * 4) = r;
}

// ---------------- kernel 1: QKV projection GEMM (C = A * B^T) + fused RoPE -------------
// m97 structure: linear LDS [128][32], global_load_lds dwordx4 staging, 2 barriers/K-step.
// Epilogue: q/k blocks apply RoPE in fp32 (pair exchange via shfl_xor(1)) then scatter
// to head-major [b][h][s][d]; v blocks scatter transposed [b][h][d][s].
__global__ __launch_bounds__(256) void gemm_qkv_kernel(
    const unsigned short* __restrict__ xb,
    const unsigned short* __restrict__ wb,
    const float* __restrict__ cs,        // [2048][32][2] cos/sin
    const int* __restrict__ pos,
    unsigned short* __restrict__ qb,
    unsigned short* __restrict__ kb,
    unsigned short* __restrict__ vtb)
{
  __shared__ unsigned short As[128 * 32];   // linear: row*32 + col (gload_lds needs linear)
  __shared__ unsigned short Bs[128 * 32];
  const int tid  = threadIdx.x;
  const int lane = tid & 63;
  const int wid  = tid >> 6;
  const int wm = wid >> 1, wn = wid & 1;
  const int m0 = blockIdx.x * 128;
  const int n0 = blockIdx.y * 128;          // 0..3071
  const int l15 = lane & 15, l4 = lane >> 4;

  // per-lane global source coords for the 2 chunks of each matrix
  const int c0 = tid;                       // chunk ids: tid, tid+256
  const int rA0 = c0 >> 2, cA0 = (c0 & 3) * 8;
  const int c1 = tid + 256;
  const int rA1 = c1 >> 2, cA1 = (c1 & 3) * 8;
  // wave-uniform LDS bases (shorts): chunk_base * 8
  const int lb0 = (wid * 64) * 8;
  const int lb1 = (256 + wid * 64) * 8;

  f32x4 acc[4][4] = {};

  for (int t = 0; t < 32; ++t) {
    __syncthreads();                        // previous iteration's readers done
    GLOAD16(xb + (m0 + rA0) * D_ + t * 32 + cA0, &As[lb0]);
    GLOAD16(xb + (m0 + rA1) * D_ + t * 32 + cA1, &As[lb1]);
    GLOAD16(wb + (n0 + rA0) * D_ + t * 32 + cA0, &Bs[lb0]);
    GLOAD16(wb + (n0 + rA1) * D_ + t * 32 + cA1, &Bs[lb1]);
    __syncthreads();                        // (compiler drains vmcnt before barrier)

    short8 af[4], bfr[4];
    #pragma unroll
    for (int mi = 0; mi < 4; ++mi) af[mi]  = *(const short8*)&As[(wm*64 + mi*16 + l15)*32 + l4*8];
    #pragma unroll
    for (int ni = 0; ni < 4; ++ni) bfr[ni] = *(const short8*)&Bs[(wn*64 + ni*16 + l15)*32 + l4*8];
    __builtin_amdgcn_s_setprio(1);
    #pragma unroll
    for (int mi = 0; mi < 4; ++mi)
      #pragma unroll
      for (int ni = 0; ni < 4; ++ni)
        acc[mi][ni] = __builtin_amdgcn_mfma_f32_16x16x32_bf16(af[mi], bfr[ni], acc[mi][ni], 0, 0, 0);
    __builtin_amdgcn_s_setprio(0);
  }

  const int bidx = m0 >> 11;
  const int sbase = (m0 & 2047) + wm * 64;

  if (n0 < 2048) {
    // ---- q or k block: fused RoPE ----
    unsigned short* dst = (n0 < 1024) ? qb : kb;
    const int nn0 = n0 & 1023;
    const float2* cs2 = (const float2*)cs;
    const float sg = (l15 & 1) ? 1.0f : -1.0f;   // even dd: -sin*par ; odd dd: +sin*par
    #pragma unroll
    for (int mi = 0; mi < 4; ++mi)
      #pragma unroll
      for (int j = 0; j < 4; ++j) {
        int s = sbase + mi*16 + l4*4 + j;
        int p = pos[s];
        #pragma unroll
        for (int ni = 0; ni < 4; ++ni) {
          int col = nn0 + wn*64 + ni*16 + l15;     // 0..1023
          int h = col >> 6, dd = col & 63;
          float val = acc[mi][ni][j];
          float par = __shfl_xor(val, 1);
          float2 cv = cs2[p*32 + (dd >> 1)];
          float r = fmaf(cv.x, val, sg * cv.y * par);
          dst[((bidx*H_ + h)*S_ + s)*DK_ + dd] = f2b(r);
        }
      }
  } else {
    // ---- v block: transposed scatter [b][h][d][s] ----
    const int nn0 = n0 & 1023;
    #pragma unroll
    for (int mi = 0; mi < 4; ++mi)
      #pragma unroll
      for (int ni = 0; ni < 4; ++ni)
        #pragma unroll
        for (int j = 0; j < 4; ++j) {
          int s = sbase + mi*16 + l4*4 + j;
          int col = nn0 + wn*64 + ni*16 + l15;
          int h = col >> 6, dd = col & 63;
          vtb[((bidx*H_ + h)*DK_ + dd)*S_ + s] = f2b(acc[mi][ni][j]);
        }
  }
}

// ---------------- kernel 3: causal flash attention (unchanged from round 2) ------------
__global__ __launch_bounds__(256, 4) void attn_kernel(
    const unsigned short* __restrict__ qb,
    const unsigned short* __restrict__ kb,
    const unsigned short* __restrict__ vtb,
    unsigned short* __restrict__ ao)
{
  __shared__ unsigned short Ks[64][72];
  __shared__ unsigned short Vs[64][72];
  __shared__ unsigned short Ps[4][16][72];
  const int tid = threadIdx.x, lane = tid & 63, wid = tid >> 6;
  const int l15 = lane & 15, l4 = lane >> 4;
  const int bh = blockIdx.y;
  const unsigned short* qp = qb  + bh * S_ * DK_;
  const unsigned short* kp = kb  + bh * S_ * DK_;
  const unsigned short* vp = vtb + bh * DK_ * S_;
  const int bidx = bh >> 4, h = bh & 15;

  for (int half = 0; half < 2; ++half) {
    const int qt = half ? (31 - (int)blockIdx.x) : (int)blockIdx.x;
    const int q0 = qt * 64;
    const int nkt = qt + 1;

    short8 qf[2];
    #pragma unroll
    for (int kbk = 0; kbk < 2; ++kbk) {
      short8 raw = *(const short8*)(qp + (q0 + wid*16 + l15)*DK_ + kbk*32 + l4*8);
      #pragma unroll
      for (int i = 0; i < 8; ++i) {
        float f = b2f((unsigned short)raw[i]) * 0.125f;
        raw[i] = (short)f2b(f);
      }
      qf[kbk] = raw;
    }

    f32x4 oacc[4] = {};
    float mrun = -1e30f, lrun = 0.0f;

    short8 kv[2], vv[2];
    #pragma unroll
    for (int jj = 0; jj < 2; ++jj) {
      int c = tid + jj * 256;
      int r = c >> 3, col = (c & 7) * 8;
      kv[jj] = *(const short8*)(kp + r*DK_ + col);
      vv[jj] = *(const short8*)(vp + r*S_ + col);
    }

    for (int kt = 0; kt < nkt; ++kt) {
      __syncthreads();
      #pragma unroll
      for (int jj = 0; jj < 2; ++jj) {
        int c = tid + jj * 256;
        int r = c >> 3, col = (c & 7) * 8;
        *(short8*)&Ks[r][col] = kv[jj];
        *(short8*)&Vs[r][col] = vv[jj];
      }
      __syncthreads();

      if (kt + 1 < nkt) {
        #pragma unroll
        for (int jj = 0; jj < 2; ++jj) {
          int c = tid + jj * 256;
          int r = c >> 3, col = (c & 7) * 8;
          kv[jj] = *(const short8*)(kp + ((kt+1)*64 + r)*DK_ + col);
          vv[jj] = *(const short8*)(vp + r*S_ + (kt+1)*64 + col);
        }
      }

      f32x4 sc[4];
      __builtin_amdgcn_s_setprio(1);
      #pragma unroll
      for (int nb = 0; nb < 4; ++nb) {
        short8 k0 = *(const short8*)&Ks[nb*16 + l15][l4*8];
        short8 k1 = *(const short8*)&Ks[nb*16 + l15][32 + l4*8];
        f32x4 z = {};
        z = __builtin_amdgcn_mfma_f32_16x16x32_bf16(k0, qf[0], z, 0, 0, 0);
        z = __builtin_amdgcn_mfma_f32_16x16x32_bf16(k1, qf[1], z, 0, 0, 0);
        sc[nb] = z;
      }
      __builtin_amdgcn_s_setprio(0);

      if (kt == nkt - 1) {
        const int qg = q0 + wid*16 + l15;
        #pragma unroll
        for (int nb = 0; nb < 4; ++nb)
          #pragma unroll
          for (int j = 0; j < 4; ++j) {
            int kg = kt*64 + nb*16 + l4*4 + j;
            if (kg > qg) sc[nb][j] = -1e30f;
          }
      }

      float tm = sc[0][0];
      #pragma unroll
      for (int nb = 0; nb < 4; ++nb)
        #pragma unroll
        for (int j = 0; j < 4; ++j) tm = fmaxf(tm, sc[nb][j]);
      tm = fmaxf(tm, __shfl_xor(tm, 16));
      tm = fmaxf(tm, __shfl_xor(tm, 32));
      float mnew = fmaxf(mrun, tm);
      float corr = __expf(mrun - mnew);
      mrun = mnew;
      float rs = 0.0f;
      #pragma unroll
      for (int nb = 0; nb < 4; ++nb)
        #pragma unroll
        for (int j = 0; j < 4; ++j) {
          float p = __expf(sc[nb][j] - mnew);
          sc[nb][j] = p;
          rs += p;
        }
      rs += __shfl_xor(rs, 16);
      rs += __shfl_xor(rs, 32);
      lrun = lrun * corr + rs;

      #pragma unroll
      for (int j = 0; j < 4; ++j) {
        float cj = __shfl(corr, l4*4 + j);
        #pragma unroll
        for (int nb = 0; nb < 4; ++nb) oacc[nb][j] *= cj;
      }

      #pragma unroll
      for (int nb = 0; nb < 4; ++nb) {
        uint2 w;
        w.x = (unsigned int)f2b(sc[nb][0]) | ((unsigned int)f2b(sc[nb][1]) << 16);
        w.y = (unsigned int)f2b(sc[nb][2]) | ((unsigned int)f2b(sc[nb][3]) << 16);
        *(uint2*)&Ps[wid][l15][nb*16 + l4*4] = w;
      }
      asm volatile("s_waitcnt lgkmcnt(0)" ::: "memory");
      short8 pa0 = *(const short8*)&Ps[wid][l15][l4*8];
      short8 pa1 = *(const short8*)&Ps[wid][l15][32 + l4*8];

      __builtin_amdgcn_s_setprio(1);
      #pragma unroll
      for (int nb = 0; nb < 4; ++nb) {
        short8 v0 = *(const short8*)&Vs[nb*16 + l15][l4*8];
        short8 v1 = *(const short8*)&Vs[nb*16 + l15][32 + l4*8];
        oacc[nb] = __builtin_amdgcn_mfma_f32_16x16x32_bf16(pa0, v0, oacc[nb], 0, 0, 0);
        oacc[nb] = __builtin_amdgcn_mfma_f32_16x16x32_bf16(pa1, v1, oacc[nb], 0, 0, 0);
      }
      __builtin_amdgcn_s_setprio(0);
    }

    #pragma unroll
    for (int j = 0; j < 4; ++j) {
      float lj = __shfl(lrun, l4*4 + j);
      float inv = 1.0f / lj;
      int row = q0 + wid*16 + l4*4 + j;
      #pragma unroll
      for (int nb = 0; nb < 4; ++nb) {
        int dim = nb*16 + l15;
        ao[((bidx*S_ + row)*H_ + h)*DK_ + dim] = f2b(oacc[nb][j] * inv);
      }
    }
  }
}

// ---------------- kernel 4: output projection (C = A * Wo^T), fp32 out -----------------
// Same m97 structure; Wo pre-converted to bf16 (wob).
__global__ __launch_bounds__(256) void gemm_out_kernel(
    const unsigned short* __restrict__ ao,
    const unsigned short* __restrict__ wob,
    float* __restrict__ out)
{
  __shared__ unsigned short As[128 * 32];
  __shared__ unsigned short Bs[128 * 32];
  const int tid = threadIdx.x, lane = tid & 63, wid = tid >> 6;
  const int wm = wid >> 1, wn = wid & 1;
  const int m0 = blockIdx.x * 128, n0 = blockIdx.y * 128;
  const int l15 = lane & 15, l4 = lane >> 4;

  const int c0 = tid;
  const int rA0 = c0 >> 2, cA0 = (c0 & 3) * 8;
  const int c1 = tid + 256;
  const int rA1 = c1 >> 2, cA1 = (c1 & 3) * 8;
  const int lb0 = (wid * 64) * 8;
  const int lb1 = (256 + wid * 64) * 8;

  f32x4 acc[4][4] = {};

  for (int t = 0; t < 32; ++t) {
    __syncthreads();
    GLOAD16(ao  + (m0 + rA0) * D_ + t * 32 + cA0, &As[lb0]);
    GLOAD16(ao  + (m0 + rA1) * D_ + t * 32 + cA1, &As[lb1]);
    GLOAD16(wob + (n0 + rA0) * D_ + t * 32 + cA0, &Bs[lb0]);
    GLOAD16(wob + (n0 + rA1) * D_ + t * 32 + cA1, &Bs[lb1]);
    __syncthreads();

    short8 af[4], bfr[4];
    #pragma unroll
    for (int mi = 0; mi < 4; ++mi) af[mi]  = *(const short8*)&As[(wm*64 + mi*16 + l15)*32 + l4*8];
    #pragma unroll
    for (int ni = 0; ni < 4; ++ni) bfr[ni] = *(const short8*)&Bs[(wn*64 + ni*16 + l15)*32 + l4*8];
    __builtin_amdgcn_s_setprio(1);
    #pragma unroll
    for (int mi = 0; mi < 4; ++mi)
      #pragma unroll
      for (int ni = 0; ni < 4; ++ni)
        acc[mi][ni] = __builtin_amdgcn_mfma_f32_16x16x32_bf16(af[mi], bfr[ni], acc[mi][ni], 0, 0, 0);
    __builtin_amdgcn_s_setprio(0);
  }

  #pragma unroll
  for (int mi = 0; mi < 4; ++mi)
    #pragma unroll
    for (int ni = 0; ni < 4; ++ni)
      #pragma unroll
      for (int j = 0; j < 4; ++j) {
        int row = m0 + wm*64 + mi*16 + l4*4 + j;
        int col = n0 + wn*64 + ni*16 + l15;
        out[row * D_ + col] = acc[mi][ni][j];
      }
}

// ---------------- launcher ----------------
extern "C" void kernel_launch(void* const* d_in, const int* in_sizes, int n_in,
                              void* d_out, int out_size, void* d_ws, size_t ws_size,
                              hipStream_t stream)
{
  const float* x  = (const float*)d_in[0];
  const float* wq = (const float*)d_in[1];
  const float* wk = (const float*)d_in[2];
  const float* wv = (const float*)d_in[3];
  const float* wo = (const float*)d_in[4];
  const float* cs = (const float*)d_in[5];
  const int*  pos = (const int*)d_in[6];
  float* out = (float*)d_out;

  // d_out as scratch until the final GEMM: xb (16.8MB) + wb (6.3MB) < 33.5MB
  unsigned short* xb = (unsigned short*)d_out;
  unsigned short* wb = xb + M_ * D_;

  // d_ws: q | k | v^T | attn_out (bf16, 16MiB each). wob reuses the q region
  // (dead after attn_kernel completes).
  unsigned short* qb  = (unsigned short*)d_ws;
  unsigned short* kbf = qb  + M_ * D_;
  unsigned short* vtb = kbf + M_ * D_;
  unsigned short* aob = vtb + M_ * D_;
  unsigned short* wob = qb;

  conv_kernel<<<dim3(2048), dim3(256), 0, stream>>>(x, wq, wk, wv, xb, wb);
  gemm_qkv_kernel<<<dim3(64, 24), dim3(256), 0, stream>>>(xb, wb, cs, pos, qb, kbf, vtb);
  attn_kernel<<<dim3(16, 64), dim3(256), 0, stream>>>(qb, kbf, vtb, aob);
  conv_wo_kernel<<<dim3(1024), dim3(256), 0, stream>>>(wo, wob);
  gemm_out_kernel<<<dim3(64, 8), dim3(256), 0, stream>>>(aob, wob, out);

  (void)in_sizes; (void)n_in; (void)out_size; (void)ws_size;
}

// Round 4
// 205.937 us; speedup vs baseline: 1.8445x; 1.0507x over previous
//
#include <hip/hip_runtime.h>

// ---------------- problem constants ----------------
constexpr int B_  = 4;
constexpr int S_  = 2048;
constexpr int D_  = 1024;
constexpr int H_  = 16;
constexpr int DK_ = 64;
constexpr int M_  = B_ * S_;          // 8192 token rows

typedef __attribute__((ext_vector_type(8))) short short8;
typedef __attribute__((ext_vector_type(4))) float f32x4;
typedef __attribute__((ext_vector_type(4))) unsigned short us4;

__device__ __forceinline__ unsigned short f2b(float f) {
  unsigned int u = __float_as_uint(f);
  u += 0x7FFFu + ((u >> 16) & 1u);          // RNE
  return (unsigned short)(u >> 16);
}
__device__ __forceinline__ float b2f(unsigned short h) {
  return __uint_as_float(((unsigned int)h) << 16);
}

// async global->LDS, 16B per lane; LDS dest must be wave-uniform base (+ lane*16 by HW)
#define GLOAD16(g, l) __builtin_amdgcn_global_load_lds( \
    (const __attribute__((address_space(1))) unsigned int*)(g), \
    (__attribute__((address_space(3))) unsigned int*)(l), 16, 0, 0)

// ---------------- kernel 0: fp32 -> bf16 conversion (x, Wq|Wk|Wv) ----------------
__global__ __launch_bounds__(256) void conv_kernel(
    const float* __restrict__ x,
    const float* __restrict__ wq, const float* __restrict__ wk, const float* __restrict__ wv,
    unsigned short* __restrict__ xb, unsigned short* __restrict__ wb)
{
  const int NX4 = (M_ * D_) / 4;
  const int NW4 = (3 * D_ * D_) / 4;
  int stride = gridDim.x * blockDim.x;
  for (int i = blockIdx.x * blockDim.x + threadIdx.x; i < NX4 + NW4; i += stride) {
    const float4* src; unsigned short* dst; int o;
    if (i < NX4) { src = (const float4*)x; dst = xb; o = i; }
    else {
      int wi = i - NX4;
      int mat = wi >> 18;
      o = wi & 262143;
      src = (const float4*)(mat == 0 ? wq : (mat == 1 ? wk : wv));
      dst = wb + mat * (D_ * D_);
    }
    float4 v = src[o];
    us4 r; r.x = f2b(v.x); r.y = f2b(v.y); r.z = f2b(v.z); r.w = f2b(v.w);
    *(us4*)(dst + o * 4) = r;
  }
}

// ---------------- kernel 0b: Wo fp32 -> bf16 ----------------
__global__ __launch_bounds__(256) void conv_wo_kernel(
    const float* __restrict__ wo, unsigned short* __restrict__ wob)
{
  int i = blockIdx.x * 256 + threadIdx.x;       // 262144 float4s
  float4 v = ((const float4*)wo)[i];
  us4 r; r.x = f2b(v.x); r.y = f2b(v.y); r.z = f2b(v.z); r.w = f2b(v.w);
  *(us4*)(wob + i * 4) = r;
}

// ---------------- kernel 1: QKV projection GEMM (C = A * B^T) + fused RoPE -------------
__global__ __launch_bounds__(256) void gemm_qkv_kernel(
    const unsigned short* __restrict__ xb,
    const unsigned short* __restrict__ wb,
    const float* __restrict__ cs,        // [2048][32][2] cos/sin
    const int* __restrict__ pos,
    unsigned short* __restrict__ qb,
    unsigned short* __restrict__ kb,
    unsigned short* __restrict__ vtb)
{
  __shared__ unsigned short As[128 * 32];
  __shared__ unsigned short Bs[128 * 32];
  const int tid  = threadIdx.x;
  const int lane = tid & 63;
  const int wid  = tid >> 6;
  const int wm = wid >> 1, wn = wid & 1;
  const int m0 = blockIdx.x * 128;
  const int n0 = blockIdx.y * 128;
  const int l15 = lane & 15, l4 = lane >> 4;

  const int c0 = tid;
  const int rA0 = c0 >> 2, cA0 = (c0 & 3) * 8;
  const int c1 = tid + 256;
  const int rA1 = c1 >> 2, cA1 = (c1 & 3) * 8;
  const int lb0 = (wid * 64) * 8;
  const int lb1 = (256 + wid * 64) * 8;

  f32x4 acc[4][4] = {};

  for (int t = 0; t < 32; ++t) {
    __syncthreads();
    GLOAD16(xb + (m0 + rA0) * D_ + t * 32 + cA0, &As[lb0]);
    GLOAD16(xb + (m0 + rA1) * D_ + t * 32 + cA1, &As[lb1]);
    GLOAD16(wb + (n0 + rA0) * D_ + t * 32 + cA0, &Bs[lb0]);
    GLOAD16(wb + (n0 + rA1) * D_ + t * 32 + cA1, &Bs[lb1]);
    __syncthreads();

    short8 af[4], bfr[4];
    #pragma unroll
    for (int mi = 0; mi < 4; ++mi) af[mi]  = *(const short8*)&As[(wm*64 + mi*16 + l15)*32 + l4*8];
    #pragma unroll
    for (int ni = 0; ni < 4; ++ni) bfr[ni] = *(const short8*)&Bs[(wn*64 + ni*16 + l15)*32 + l4*8];
    __builtin_amdgcn_s_setprio(1);
    #pragma unroll
    for (int mi = 0; mi < 4; ++mi)
      #pragma unroll
      for (int ni = 0; ni < 4; ++ni)
        acc[mi][ni] = __builtin_amdgcn_mfma_f32_16x16x32_bf16(af[mi], bfr[ni], acc[mi][ni], 0, 0, 0);
    __builtin_amdgcn_s_setprio(0);
  }

  const int bidx = m0 >> 11;
  const int sbase = (m0 & 2047) + wm * 64;

  if (n0 < 2048) {
    unsigned short* dst = (n0 < 1024) ? qb : kb;
    const int nn0 = n0 & 1023;
    const float2* cs2 = (const float2*)cs;
    const float sg = (l15 & 1) ? 1.0f : -1.0f;
    #pragma unroll
    for (int mi = 0; mi < 4; ++mi)
      #pragma unroll
      for (int j = 0; j < 4; ++j) {
        int s = sbase + mi*16 + l4*4 + j;
        int p = pos[s];
        #pragma unroll
        for (int ni = 0; ni < 4; ++ni) {
          int col = nn0 + wn*64 + ni*16 + l15;
          int h = col >> 6, dd = col & 63;
          float val = acc[mi][ni][j];
          float par = __shfl_xor(val, 1);
          float2 cv = cs2[p*32 + (dd >> 1)];
          float r = fmaf(cv.x, val, sg * cv.y * par);
          dst[((bidx*H_ + h)*S_ + s)*DK_ + dd] = f2b(r);
        }
      }
  } else {
    const int nn0 = n0 & 1023;
    #pragma unroll
    for (int mi = 0; mi < 4; ++mi)
      #pragma unroll
      for (int ni = 0; ni < 4; ++ni)
        #pragma unroll
        for (int j = 0; j < 4; ++j) {
          int s = sbase + mi*16 + l4*4 + j;
          int col = nn0 + wn*64 + ni*16 + l15;
          int h = col >> 6, dd = col & 63;
          vtb[((bidx*H_ + h)*DK_ + dd)*S_ + s] = f2b(acc[mi][ni][j]);
        }
  }
}

// ---------------- kernel 3: causal flash attention v3 ----------------
// QBLK=128 (each wave: two 16-row Q groups), KVBLK=64, grid 512 1D with XCD swizzle:
// each XCD owns 8 consecutive heads -> K/V working set 4MB = its L2. Defer-max (T13).
__global__ __launch_bounds__(256, 2) void attn_kernel(
    const unsigned short* __restrict__ qb,
    const unsigned short* __restrict__ kb,
    const unsigned short* __restrict__ vtb,
    unsigned short* __restrict__ ao)
{
  __shared__ unsigned short Ks[64][72];        // [key][dim]
  __shared__ unsigned short Vs[64][72];        // [dim][key]
  __shared__ unsigned short Ps[4][2][16][72];  // [wave][group][qrow][key]
  const int tid = threadIdx.x, lane = tid & 63, wid = tid >> 6;
  const int l15 = lane & 15, l4 = lane >> 4;

  const int id  = blockIdx.x;                  // 0..511
  const int swz = (id & 7) * 64 + (id >> 3);   // XCD k -> contiguous chunk [64k,64k+64)
  const int bh  = swz >> 3;                    // 8 heads per XCD
  const int qpair = swz & 7;

  const unsigned short* qp = qb  + bh * S_ * DK_;
  const unsigned short* kp = kb  + bh * S_ * DK_;
  const unsigned short* vp = vtb + bh * DK_ * S_;
  const int bidx = bh >> 4, h = bh & 15;

  for (int half = 0; half < 2; ++half) {
    const int qt = half ? (15 - qpair) : qpair;   // q-tile of 128 rows
    const int q0 = qt * 128;
    const int nkt = 2 * qt + 2;

    short8 kv[2], vv[2];
    // prologue loads for kt = 0
    #pragma unroll
    for (int jj = 0; jj < 2; ++jj) {
      int c = tid + jj * 256;
      int r = c >> 3, col = (c & 7) * 8;
      kv[jj] = *(const short8*)(kp + r*DK_ + col);
      vv[jj] = *(const short8*)(vp + r*S_ + col);
    }

    // Q B-frags, two 16-row groups per wave, pre-scaled by 1/8
    short8 qf[2][2];
    #pragma unroll
    for (int y = 0; y < 2; ++y)
      #pragma unroll
      for (int kbk = 0; kbk < 2; ++kbk) {
        short8 raw = *(const short8*)(qp + (q0 + y*64 + wid*16 + l15)*DK_ + kbk*32 + l4*8);
        #pragma unroll
        for (int i = 0; i < 8; ++i) {
          float f = b2f((unsigned short)raw[i]) * 0.125f;
          raw[i] = (short)f2b(f);
        }
        qf[y][kbk] = raw;
      }

    f32x4 oacc[2][4] = {};
    float mrun[2] = {-1e30f, -1e30f}, lrun[2] = {0.0f, 0.0f};

    for (int kt = 0; kt < nkt; ++kt) {
      __syncthreads();
      #pragma unroll
      for (int jj = 0; jj < 2; ++jj) {
        int c = tid + jj * 256;
        int r = c >> 3, col = (c & 7) * 8;
        *(short8*)&Ks[r][col] = kv[jj];
        *(short8*)&Vs[r][col] = vv[jj];
      }
      __syncthreads();

      if (kt + 1 < nkt) {                     // prefetch next tile under compute
        #pragma unroll
        for (int jj = 0; jj < 2; ++jj) {
          int c = tid + jj * 256;
          int r = c >> 3, col = (c & 7) * 8;
          kv[jj] = *(const short8*)(kp + ((kt+1)*64 + r)*DK_ + col);
          vv[jj] = *(const short8*)(vp + r*S_ + (kt+1)*64 + col);
        }
      }

      #pragma unroll
      for (int y = 0; y < 2; ++y) {
        if (kt > 2*qt + y) continue;          // fully masked group: skip (wave-uniform)

        // swapped QK^T: lane owns q-row (l15), 16 keys in-register
        f32x4 sc[4];
        __builtin_amdgcn_s_setprio(1);
        #pragma unroll
        for (int nb = 0; nb < 4; ++nb) {
          short8 k0 = *(const short8*)&Ks[nb*16 + l15][l4*8];
          short8 k1 = *(const short8*)&Ks[nb*16 + l15][32 + l4*8];
          f32x4 z = {};
          z = __builtin_amdgcn_mfma_f32_16x16x32_bf16(k0, qf[y][0], z, 0, 0, 0);
          z = __builtin_amdgcn_mfma_f32_16x16x32_bf16(k1, qf[y][1], z, 0, 0, 0);
          sc[nb] = z;
        }
        __builtin_amdgcn_s_setprio(0);

        if (kt == 2*qt + y) {                 // diagonal tile mask
          const int qg = q0 + y*64 + wid*16 + l15;
          #pragma unroll
          for (int nb = 0; nb < 4; ++nb)
            #pragma unroll
            for (int j = 0; j < 4; ++j) {
              int kg = kt*64 + nb*16 + l4*4 + j;
              if (kg > qg) sc[nb][j] = -1e30f;
            }
        }

        // online softmax with defer-max (THR=8)
        float tm = sc[0][0];
        #pragma unroll
        for (int nb = 0; nb < 4; ++nb)
          #pragma unroll
          for (int j = 0; j < 4; ++j) tm = fmaxf(tm, sc[nb][j]);
        tm = fmaxf(tm, __shfl_xor(tm, 16));
        tm = fmaxf(tm, __shfl_xor(tm, 32));
        if (!__all(tm - mrun[y] <= 8.0f)) {
          float mnew = fmaxf(mrun[y], tm);
          float corr = __expf(mrun[y] - mnew);
          mrun[y] = mnew;
          lrun[y] *= corr;
          #pragma unroll
          for (int j = 0; j < 4; ++j) {
            float cj = __shfl(corr, l4*4 + j);
            #pragma unroll
            for (int nb = 0; nb < 4; ++nb) oacc[y][nb][j] *= cj;
          }
        }
        float rs = 0.0f;
        #pragma unroll
        for (int nb = 0; nb < 4; ++nb)
          #pragma unroll
          for (int j = 0; j < 4; ++j) {
            float p = __expf(sc[nb][j] - mrun[y]);
            sc[nb][j] = p;
            rs += p;
          }
        rs += __shfl_xor(rs, 16);
        rs += __shfl_xor(rs, 32);
        lrun[y] += rs;

        // P -> Ps (vector b64), read back as A-frags
        #pragma unroll
        for (int nb = 0; nb < 4; ++nb) {
          uint2 w;
          w.x = (unsigned int)f2b(sc[nb][0]) | ((unsigned int)f2b(sc[nb][1]) << 16);
          w.y = (unsigned int)f2b(sc[nb][2]) | ((unsigned int)f2b(sc[nb][3]) << 16);
          *(uint2*)&Ps[wid][y][l15][nb*16 + l4*4] = w;
        }
        asm volatile("s_waitcnt lgkmcnt(0)" ::: "memory");
        short8 pa0 = *(const short8*)&Ps[wid][y][l15][l4*8];
        short8 pa1 = *(const short8*)&Ps[wid][y][l15][32 + l4*8];

        // O += P * V
        __builtin_amdgcn_s_setprio(1);
        #pragma unroll
        for (int nb = 0; nb < 4; ++nb) {
          short8 v0 = *(const short8*)&Vs[nb*16 + l15][l4*8];
          short8 v1 = *(const short8*)&Vs[nb*16 + l15][32 + l4*8];
          oacc[y][nb] = __builtin_amdgcn_mfma_f32_16x16x32_bf16(pa0, v0, oacc[y][nb], 0, 0, 0);
          oacc[y][nb] = __builtin_amdgcn_mfma_f32_16x16x32_bf16(pa1, v1, oacc[y][nb], 0, 0, 0);
        }
        __builtin_amdgcn_s_setprio(0);
      }
    }

    #pragma unroll
    for (int y = 0; y < 2; ++y)
      #pragma unroll
      for (int j = 0; j < 4; ++j) {
        float lj = __shfl(lrun[y], l4*4 + j);
        float inv = 1.0f / lj;
        int row = q0 + y*64 + wid*16 + l4*4 + j;
        #pragma unroll
        for (int nb = 0; nb < 4; ++nb) {
          int dim = nb*16 + l15;
          ao[((bidx*S_ + row)*H_ + h)*DK_ + dim] = f2b(oacc[y][nb][j] * inv);
        }
      }
  }
}

// ---------------- kernel 4: output projection (C = A * Wo^T), fp32 out -----------------
__global__ __launch_bounds__(256) void gemm_out_kernel(
    const unsigned short* __restrict__ ao,
    const unsigned short* __restrict__ wob,
    float* __restrict__ out)
{
  __shared__ unsigned short As[128 * 32];
  __shared__ unsigned short Bs[128 * 32];
  const int tid = threadIdx.x, lane = tid & 63, wid = tid >> 6;
  const int wm = wid >> 1, wn = wid & 1;
  const int m0 = blockIdx.x * 128, n0 = blockIdx.y * 128;
  const int l15 = lane & 15, l4 = lane >> 4;

  const int c0 = tid;
  const int rA0 = c0 >> 2, cA0 = (c0 & 3) * 8;
  const int c1 = tid + 256;
  const int rA1 = c1 >> 2, cA1 = (c1 & 3) * 8;
  const int lb0 = (wid * 64) * 8;
  const int lb1 = (256 + wid * 64) * 8;

  f32x4 acc[4][4] = {};

  for (int t = 0; t < 32; ++t) {
    __syncthreads();
    GLOAD16(ao  + (m0 + rA0) * D_ + t * 32 + cA0, &As[lb0]);
    GLOAD16(ao  + (m0 + rA1) * D_ + t * 32 + cA1, &As[lb1]);
    GLOAD16(wob + (n0 + rA0) * D_ + t * 32 + cA0, &Bs[lb0]);
    GLOAD16(wob + (n0 + rA1) * D_ + t * 32 + cA1, &Bs[lb1]);
    __syncthreads();

    short8 af[4], bfr[4];
    #pragma unroll
    for (int mi = 0; mi < 4; ++mi) af[mi]  = *(const short8*)&As[(wm*64 + mi*16 + l15)*32 + l4*8];
    #pragma unroll
    for (int ni = 0; ni < 4; ++ni) bfr[ni] = *(const short8*)&Bs[(wn*64 + ni*16 + l15)*32 + l4*8];
    __builtin_amdgcn_s_setprio(1);
    #pragma unroll
    for (int mi = 0; mi < 4; ++mi)
      #pragma unroll
      for (int ni = 0; ni < 4; ++ni)
        acc[mi][ni] = __builtin_amdgcn_mfma_f32_16x16x32_bf16(af[mi], bfr[ni], acc[mi][ni], 0, 0, 0);
    __builtin_amdgcn_s_setprio(0);
  }

  #pragma unroll
  for (int mi = 0; mi < 4; ++mi)
    #pragma unroll
    for (int ni = 0; ni < 4; ++ni)
      #pragma unroll
      for (int j = 0; j < 4; ++j) {
        int row = m0 + wm*64 + mi*16 + l4*4 + j;
        int col = n0 + wn*64 + ni*16 + l15;
        out[row * D_ + col] = acc[mi][ni][j];
      }
}

// ---------------- launcher ----------------
extern "C" void kernel_launch(void* const* d_in, const int* in_sizes, int n_in,
                              void* d_out, int out_size, void* d_ws, size_t ws_size,
                              hipStream_t stream)
{
  const float* x  = (const float*)d_in[0];
  const float* wq = (const float*)d_in[1];
  const float* wk = (const float*)d_in[2];
  const float* wv = (const float*)d_in[3];
  const float* wo = (const float*)d_in[4];
  const float* cs = (const float*)d_in[5];
  const int*  pos = (const int*)d_in[6];
  float* out = (float*)d_out;

  unsigned short* xb = (unsigned short*)d_out;   // d_out as scratch until final GEMM
  unsigned short* wb = xb + M_ * D_;

  unsigned short* qb  = (unsigned short*)d_ws;
  unsigned short* kbf = qb  + M_ * D_;
  unsigned short* vtb = kbf + M_ * D_;
  unsigned short* aob = vtb + M_ * D_;
  unsigned short* wob = qb;                      // dead q region after attn

  conv_kernel<<<dim3(2048), dim3(256), 0, stream>>>(x, wq, wk, wv, xb, wb);
  gemm_qkv_kernel<<<dim3(64, 24), dim3(256), 0, stream>>>(xb, wb, cs, pos, qb, kbf, vtb);
  attn_kernel<<<dim3(512), dim3(256), 0, stream>>>(qb, kbf, vtb, aob);
  conv_wo_kernel<<<dim3(1024), dim3(256), 0, stream>>>(wo, wob);
  gemm_out_kernel<<<dim3(64, 8), dim3(256), 0, stream>>>(aob, wob, out);

  (void)in_sizes; (void)n_in; (void)out_size; (void)ws_size;
}

// Round 5
// 201.947 us; speedup vs baseline: 1.8809x; 1.0198x over previous
//
#include <hip/hip_runtime.h>

// ---------------- problem constants ----------------
constexpr int B_  = 4;
constexpr int S_  = 2048;
constexpr int D_  = 1024;
constexpr int H_  = 16;
constexpr int DK_ = 64;
constexpr int M_  = B_ * S_;          // 8192 token rows

typedef __attribute__((ext_vector_type(8))) short short8;
typedef __attribute__((ext_vector_type(4))) float f32x4;
typedef __attribute__((ext_vector_type(4))) unsigned short us4;

__device__ __forceinline__ unsigned short f2b(float f) {
  unsigned int u = __float_as_uint(f);
  u += 0x7FFFu + ((u >> 16) & 1u);          // RNE
  return (unsigned short)(u >> 16);
}
__device__ __forceinline__ float b2f(unsigned short h) {
  return __uint_as_float(((unsigned int)h) << 16);
}
// packed f32x2 -> bf16x2 (RNE), single HW instr
__device__ __forceinline__ unsigned int cvtpk(float lo, float hi) {
  unsigned int w;
  asm("v_cvt_pk_bf16_f32 %0, %1, %2" : "=v"(w) : "v"(lo), "v"(hi));
  return w;
}
// D = 2^S0
__device__ __forceinline__ float exp2v(float x) {
  float r;
  asm("v_exp_f32 %0, %1" : "=v"(r) : "v"(x));
  return r;
}

// async global->LDS, 16B per lane; LDS dest must be wave-uniform base (+ lane*16 by HW)
#define GLOAD16(g, l) __builtin_amdgcn_global_load_lds( \
    (const __attribute__((address_space(1))) unsigned int*)(g), \
    (__attribute__((address_space(3))) unsigned int*)(l), 16, 0, 0)

// ---------------- kernel 0: fp32 -> bf16 conversion (x, Wq|Wk|Wv) ----------------
__global__ __launch_bounds__(256) void conv_kernel(
    const float* __restrict__ x,
    const float* __restrict__ wq, const float* __restrict__ wk, const float* __restrict__ wv,
    unsigned short* __restrict__ xb, unsigned short* __restrict__ wb)
{
  const int NX4 = (M_ * D_) / 4;
  const int NW4 = (3 * D_ * D_) / 4;
  int stride = gridDim.x * blockDim.x;
  for (int i = blockIdx.x * blockDim.x + threadIdx.x; i < NX4 + NW4; i += stride) {
    const float4* src; unsigned short* dst; int o;
    if (i < NX4) { src = (const float4*)x; dst = xb; o = i; }
    else {
      int wi = i - NX4;
      int mat = wi >> 18;
      o = wi & 262143;
      src = (const float4*)(mat == 0 ? wq : (mat == 1 ? wk : wv));
      dst = wb + mat * (D_ * D_);
    }
    float4 v = src[o];
    us4 r; r.x = f2b(v.x); r.y = f2b(v.y); r.z = f2b(v.z); r.w = f2b(v.w);
    *(us4*)(dst + o * 4) = r;
  }
}

// ---------------- kernel 0b: Wo fp32 -> bf16 ----------------
__global__ __launch_bounds__(256) void conv_wo_kernel(
    const float* __restrict__ wo, unsigned short* __restrict__ wob)
{
  int i = blockIdx.x * 256 + threadIdx.x;       // 262144 float4s
  float4 v = ((const float4*)wo)[i];
  us4 r; r.x = f2b(v.x); r.y = f2b(v.y); r.z = f2b(v.z); r.w = f2b(v.w);
  *(us4*)(wob + i * 4) = r;
}

// ---------------- kernel 1: QKV projection GEMM (C = A * B^T) + fused RoPE -------------
__global__ __launch_bounds__(256) void gemm_qkv_kernel(
    const unsigned short* __restrict__ xb,
    const unsigned short* __restrict__ wb,
    const float* __restrict__ cs,        // [2048][32][2] cos/sin
    const int* __restrict__ pos,
    unsigned short* __restrict__ qb,
    unsigned short* __restrict__ kb,
    unsigned short* __restrict__ vtb)
{
  __shared__ unsigned short As[128 * 32];
  __shared__ unsigned short Bs[128 * 32];
  const int tid  = threadIdx.x;
  const int lane = tid & 63;
  const int wid  = tid >> 6;
  const int wm = wid >> 1, wn = wid & 1;
  const int m0 = blockIdx.x * 128;
  const int n0 = blockIdx.y * 128;
  const int l15 = lane & 15, l4 = lane >> 4;

  const int c0 = tid;
  const int rA0 = c0 >> 2, cA0 = (c0 & 3) * 8;
  const int c1 = tid + 256;
  const int rA1 = c1 >> 2, cA1 = (c1 & 3) * 8;
  const int lb0 = (wid * 64) * 8;
  const int lb1 = (256 + wid * 64) * 8;

  f32x4 acc[4][4] = {};

  for (int t = 0; t < 32; ++t) {
    __syncthreads();
    GLOAD16(xb + (m0 + rA0) * D_ + t * 32 + cA0, &As[lb0]);
    GLOAD16(xb + (m0 + rA1) * D_ + t * 32 + cA1, &As[lb1]);
    GLOAD16(wb + (n0 + rA0) * D_ + t * 32 + cA0, &Bs[lb0]);
    GLOAD16(wb + (n0 + rA1) * D_ + t * 32 + cA1, &Bs[lb1]);
    __syncthreads();

    short8 af[4], bfr[4];
    #pragma unroll
    for (int mi = 0; mi < 4; ++mi) af[mi]  = *(const short8*)&As[(wm*64 + mi*16 + l15)*32 + l4*8];
    #pragma unroll
    for (int ni = 0; ni < 4; ++ni) bfr[ni] = *(const short8*)&Bs[(wn*64 + ni*16 + l15)*32 + l4*8];
    __builtin_amdgcn_s_setprio(1);
    #pragma unroll
    for (int mi = 0; mi < 4; ++mi)
      #pragma unroll
      for (int ni = 0; ni < 4; ++ni)
        acc[mi][ni] = __builtin_amdgcn_mfma_f32_16x16x32_bf16(af[mi], bfr[ni], acc[mi][ni], 0, 0, 0);
    __builtin_amdgcn_s_setprio(0);
  }

  const int bidx = m0 >> 11;
  const int sbase = (m0 & 2047) + wm * 64;

  if (n0 < 2048) {
    // ---- q or k block: fused RoPE, [b][h][s][d] scatter ----
    unsigned short* dst = (n0 < 1024) ? qb : kb;
    const int nn0 = n0 & 1023;
    const float2* cs2 = (const float2*)cs;
    const float sg = (l15 & 1) ? 1.0f : -1.0f;
    #pragma unroll
    for (int mi = 0; mi < 4; ++mi)
      #pragma unroll
      for (int j = 0; j < 4; ++j) {
        int s = sbase + mi*16 + l4*4 + j;
        int p = pos[s];
        #pragma unroll
        for (int ni = 0; ni < 4; ++ni) {
          int col = nn0 + wn*64 + ni*16 + l15;
          int h = col >> 6, dd = col & 63;
          float val = acc[mi][ni][j];
          float par = __shfl_xor(val, 1);
          float2 cv = cs2[p*32 + (dd >> 1)];
          float r = fmaf(cv.x, val, sg * cv.y * par);
          dst[((bidx*H_ + h)*S_ + s)*DK_ + dd] = f2b(r);
        }
      }
  } else {
    // ---- v block: transposed scatter [b][h][d][s]; 4 consecutive tokens per lane
    // -> pack into one 8B store via 2x v_cvt_pk_bf16_f32
    const int nn0 = n0 & 1023;
    const int hB = (nn0 + wn*64) >> 6;           // ni*16+l15 < 64, so head fixed per wave-col
    #pragma unroll
    for (int mi = 0; mi < 4; ++mi) {
      int s4 = sbase + mi*16 + l4*4;             // 4 consecutive tokens
      #pragma unroll
      for (int ni = 0; ni < 4; ++ni) {
        int dd = ni*16 + l15;
        uint2 w;
        w.x = cvtpk(acc[mi][ni][0], acc[mi][ni][1]);
        w.y = cvtpk(acc[mi][ni][2], acc[mi][ni][3]);
        *(uint2*)(vtb + ((bidx*H_ + hB)*DK_ + dd)*S_ + s4) = w;
      }
    }
  }
}

// ---------------- kernel 3: causal flash attention v4 ----------------
// Grid 1024: one 128-row q-tile per block; 8 heads per XCD (4MB K/V = L2);
// heavy q-tiles dispatched first. exp2-domain softmax (log2e folded into Q scale),
// cvt_pk P-pack, defer-max (THR=8 in log2 domain).
__global__ __launch_bounds__(256, 4) void attn_kernel(
    const unsigned short* __restrict__ qb,
    const unsigned short* __restrict__ kb,
    const unsigned short* __restrict__ vtb,
    unsigned short* __restrict__ ao)
{
  __shared__ unsigned short Ks[64][72];        // [key][dim]
  __shared__ unsigned short Vs[64][72];        // [dim][key]
  __shared__ unsigned short Ps[4][16][72];     // per-wave P relayout (y-groups reuse it)
  const int tid = threadIdx.x, lane = tid & 63, wid = tid >> 6;
  const int l15 = lane & 15, l4 = lane >> 4;

  const int id  = blockIdx.x;                  // 0..1023
  const int xcd = id & 7, jj2 = id >> 3;       // jj2: 0..127
  const int bh  = xcd * 8 + (jj2 & 7);         // 8 consecutive heads per XCD
  const int qt  = 15 - (jj2 >> 3);             // heavy tiles first
  const int q0  = qt * 128;
  const int nkt = 2 * qt + 2;

  const unsigned short* qp = qb  + bh * S_ * DK_;
  const unsigned short* kp = kb  + bh * S_ * DK_;
  const unsigned short* vp = vtb + bh * DK_ * S_;
  const int bidx = bh >> 4, h = bh & 15;

  // Q B-frags, two 16-row groups per wave, pre-scaled by (1/8)*log2(e)
  const float QSC = 0.18033688f;
  short8 qf[2][2];
  #pragma unroll
  for (int y = 0; y < 2; ++y)
    #pragma unroll
    for (int kbk = 0; kbk < 2; ++kbk) {
      short8 raw = *(const short8*)(qp + (q0 + y*64 + wid*16 + l15)*DK_ + kbk*32 + l4*8);
      #pragma unroll
      for (int i = 0; i < 8; ++i) {
        float f = b2f((unsigned short)raw[i]) * QSC;
        raw[i] = (short)f2b(f);
      }
      qf[y][kbk] = raw;
    }

  f32x4 oacc[2][4] = {};
  float mrun[2] = {-1e30f, -1e30f}, lrun[2] = {0.0f, 0.0f};

  short8 kv[2], vv[2];
  #pragma unroll
  for (int jj = 0; jj < 2; ++jj) {             // prologue: tile 0
    int c = tid + jj * 256;
    int r = c >> 3, col = (c & 7) * 8;
    kv[jj] = *(const short8*)(kp + r*DK_ + col);
    vv[jj] = *(const short8*)(vp + r*S_ + col);
  }

  for (int kt = 0; kt < nkt; ++kt) {
    __syncthreads();
    #pragma unroll
    for (int jj = 0; jj < 2; ++jj) {
      int c = tid + jj * 256;
      int r = c >> 3, col = (c & 7) * 8;
      *(short8*)&Ks[r][col] = kv[jj];
      *(short8*)&Vs[r][col] = vv[jj];
    }
    __syncthreads();

    if (kt + 1 < nkt) {                        // T14: prefetch next tile under compute
      #pragma unroll
      for (int jj = 0; jj < 2; ++jj) {
        int c = tid + jj * 256;
        int r = c >> 3, col = (c & 7) * 8;
        kv[jj] = *(const short8*)(kp + ((kt+1)*64 + r)*DK_ + col);
        vv[jj] = *(const short8*)(vp + r*S_ + (kt+1)*64 + col);
      }
    }

    #pragma unroll
    for (int y = 0; y < 2; ++y) {
      if (kt > 2*qt + y) continue;             // fully masked group (only y=0 at last kt)

      // swapped QK^T: lane owns q-row (l15), 16 keys in-register
      f32x4 sc[4];
      __builtin_amdgcn_s_setprio(1);
      #pragma unroll
      for (int nb = 0; nb < 4; ++nb) {
        short8 k0 = *(const short8*)&Ks[nb*16 + l15][l4*8];
        short8 k1 = *(const short8*)&Ks[nb*16 + l15][32 + l4*8];
        f32x4 z = {};
        z = __builtin_amdgcn_mfma_f32_16x16x32_bf16(k0, qf[y][0], z, 0, 0, 0);
        z = __builtin_amdgcn_mfma_f32_16x16x32_bf16(k1, qf[y][1], z, 0, 0, 0);
        sc[nb] = z;
      }
      __builtin_amdgcn_s_setprio(0);

      if (kt == 2*qt + y) {                    // diagonal tile mask
        const int qg = q0 + y*64 + wid*16 + l15;
        #pragma unroll
        for (int nb = 0; nb < 4; ++nb)
          #pragma unroll
          for (int j = 0; j < 4; ++j) {
            int kg = kt*64 + nb*16 + l4*4 + j;
            if (kg > qg) sc[nb][j] = -1e30f;
          }
      }

      // online softmax in log2 domain, defer-max THR=8 (factor 256)
      float tm = sc[0][0];
      #pragma unroll
      for (int nb = 0; nb < 4; ++nb)
        #pragma unroll
        for (int j = 0; j < 4; ++j) tm = fmaxf(tm, sc[nb][j]);
      tm = fmaxf(tm, __shfl_xor(tm, 16));
      tm = fmaxf(tm, __shfl_xor(tm, 32));
      if (!__all(tm - mrun[y] <= 8.0f)) {
        float mnew = fmaxf(mrun[y], tm);
        float corr = exp2v(mrun[y] - mnew);
        mrun[y] = mnew;
        lrun[y] *= corr;
        #pragma unroll
        for (int j = 0; j < 4; ++j) {
          float cj = __shfl(corr, l4*4 + j);
          #pragma unroll
          for (int nb = 0; nb < 4; ++nb) oacc[y][nb][j] *= cj;
        }
      }
      float rs = 0.0f;
      #pragma unroll
      for (int nb = 0; nb < 4; ++nb)
        #pragma unroll
        for (int j = 0; j < 4; ++j) {
          float p = exp2v(sc[nb][j] - mrun[y]);
          sc[nb][j] = p;
          rs += p;
        }
      rs += __shfl_xor(rs, 16);
      rs += __shfl_xor(rs, 32);
      lrun[y] += rs;

      // P -> Ps via cvt_pk (b64 writes), read back as A-frags (same-wave DS in-order)
      #pragma unroll
      for (int nb = 0; nb < 4; ++nb) {
        uint2 w;
        w.x = cvtpk(sc[nb][0], sc[nb][1]);
        w.y = cvtpk(sc[nb][2], sc[nb][3]);
        *(uint2*)&Ps[wid][l15][nb*16 + l4*4] = w;
      }
      asm volatile("s_waitcnt lgkmcnt(0)" ::: "memory");
      short8 pa0 = *(const short8*)&Ps[wid][l15][l4*8];
      short8 pa1 = *(const short8*)&Ps[wid][l15][32 + l4*8];

      // O += P * V
      __builtin_amdgcn_s_setprio(1);
      #pragma unroll
      for (int nb = 0; nb < 4; ++nb) {
        short8 v0 = *(const short8*)&Vs[nb*16 + l15][l4*8];
        short8 v1 = *(const short8*)&Vs[nb*16 + l15][32 + l4*8];
        oacc[y][nb] = __builtin_amdgcn_mfma_f32_16x16x32_bf16(pa0, v0, oacc[y][nb], 0, 0, 0);
        oacc[y][nb] = __builtin_amdgcn_mfma_f32_16x16x32_bf16(pa1, v1, oacc[y][nb], 0, 0, 0);
      }
      __builtin_amdgcn_s_setprio(0);
    }
  }

  #pragma unroll
  for (int y = 0; y < 2; ++y)
    #pragma unroll
    for (int j = 0; j < 4; ++j) {
      float lj = __shfl(lrun[y], l4*4 + j);
      float inv = 1.0f / lj;
      int row = q0 + y*64 + wid*16 + l4*4 + j;
      #pragma unroll
      for (int nb = 0; nb < 4; ++nb) {
        int dim = nb*16 + l15;
        ao[((bidx*S_ + row)*H_ + h)*DK_ + dim] = f2b(oacc[y][nb][j] * inv);
      }
    }
}

// ---------------- kernel 4: output projection (C = A * Wo^T), fp32 out -----------------
__global__ __launch_bounds__(256) void gemm_out_kernel(
    const unsigned short* __restrict__ ao,
    const unsigned short* __restrict__ wob,
    float* __restrict__ out)
{
  __shared__ unsigned short As[128 * 32];
  __shared__ unsigned short Bs[128 * 32];
  const int tid = threadIdx.x, lane = tid & 63, wid = tid >> 6;
  const int wm = wid >> 1, wn = wid & 1;
  const int m0 = blockIdx.x * 128, n0 = blockIdx.y * 128;
  const int l15 = lane & 15, l4 = lane >> 4;

  const int c0 = tid;
  const int rA0 = c0 >> 2, cA0 = (c0 & 3) * 8;
  const int c1 = tid + 256;
  const int rA1 = c1 >> 2, cA1 = (c1 & 3) * 8;
  const int lb0 = (wid * 64) * 8;
  const int lb1 = (256 + wid * 64) * 8;

  f32x4 acc[4][4] = {};

  for (int t = 0; t < 32; ++t) {
    __syncthreads();
    GLOAD16(ao  + (m0 + rA0) * D_ + t * 32 + cA0, &As[lb0]);
    GLOAD16(ao  + (m0 + rA1) * D_ + t * 32 + cA1, &As[lb1]);
    GLOAD16(wob + (n0 + rA0) * D_ + t * 32 + cA0, &Bs[lb0]);
    GLOAD16(wob + (n0 + rA1) * D_ + t * 32 + cA1, &Bs[lb1]);
    __syncthreads();

    short8 af[4], bfr[4];
    #pragma unroll
    for (int mi = 0; mi < 4; ++mi) af[mi]  = *(const short8*)&As[(wm*64 + mi*16 + l15)*32 + l4*8];
    #pragma unroll
    for (int ni = 0; ni < 4; ++ni) bfr[ni] = *(const short8*)&Bs[(wn*64 + ni*16 + l15)*32 + l4*8];
    __builtin_amdgcn_s_setprio(1);
    #pragma unroll
    for (int mi = 0; mi < 4; ++mi)
      #pragma unroll
      for (int ni = 0; ni < 4; ++ni)
        acc[mi][ni] = __builtin_amdgcn_mfma_f32_16x16x32_bf16(af[mi], bfr[ni], acc[mi][ni], 0, 0, 0);
    __builtin_amdgcn_s_setprio(0);
  }

  #pragma unroll
  for (int mi = 0; mi < 4; ++mi)
    #pragma unroll
    for (int ni = 0; ni < 4; ++ni)
      #pragma unroll
      for (int j = 0; j < 4; ++j) {
        int row = m0 + wm*64 + mi*16 + l4*4 + j;
        int col = n0 + wn*64 + ni*16 + l15;
        out[row * D_ + col] = acc[mi][ni][j];
      }
}

// ---------------- launcher ----------------
extern "C" void kernel_launch(void* const* d_in, const int* in_sizes, int n_in,
                              void* d_out, int out_size, void* d_ws, size_t ws_size,
                              hipStream_t stream)
{
  const float* x  = (const float*)d_in[0];
  const float* wq = (const float*)d_in[1];
  const float* wk = (const float*)d_in[2];
  const float* wv = (const float*)d_in[3];
  const float* wo = (const float*)d_in[4];
  const float* cs = (const float*)d_in[5];
  const int*  pos = (const int*)d_in[6];
  float* out = (float*)d_out;

  unsigned short* xb = (unsigned short*)d_out;   // d_out as scratch until final GEMM
  unsigned short* wb = xb + M_ * D_;

  unsigned short* qb  = (unsigned short*)d_ws;
  unsigned short* kbf = qb  + M_ * D_;
  unsigned short* vtb = kbf + M_ * D_;
  unsigned short* aob = vtb + M_ * D_;
  unsigned short* wob = qb;                      // dead q region after attn

  conv_kernel<<<dim3(2048), dim3(256), 0, stream>>>(x, wq, wk, wv, xb, wb);
  gemm_qkv_kernel<<<dim3(64, 24), dim3(256), 0, stream>>>(xb, wb, cs, pos, qb, kbf, vtb);
  attn_kernel<<<dim3(1024), dim3(256), 0, stream>>>(qb, kbf, vtb, aob);
  conv_wo_kernel<<<dim3(1024), dim3(256), 0, stream>>>(wo, wob);
  gemm_out_kernel<<<dim3(64, 8), dim3(256), 0, stream>>>(aob, wob, out);

  (void)in_sizes; (void)n_in; (void)out_size; (void)ws_size;
}

// Round 6
// 184.949 us; speedup vs baseline: 2.0538x; 1.0919x over previous
//
#include <hip/hip_runtime.h>

// ---------------- problem constants ----------------
constexpr int B_  = 4;
constexpr int S_  = 2048;
constexpr int D_  = 1024;
constexpr int H_  = 16;
constexpr int DK_ = 64;
constexpr int M_  = B_ * S_;          // 8192 token rows

typedef __attribute__((ext_vector_type(8))) short short8;
typedef __attribute__((ext_vector_type(4))) float f32x4;
typedef __attribute__((ext_vector_type(4))) unsigned short us4;

__device__ __forceinline__ unsigned short f2b(float f) {
  unsigned int u = __float_as_uint(f);
  u += 0x7FFFu + ((u >> 16) & 1u);          // RNE
  return (unsigned short)(u >> 16);
}
__device__ __forceinline__ float b2f(unsigned short h) {
  return __uint_as_float(((unsigned int)h) << 16);
}
// packed f32x2 -> bf16x2 (RNE), single HW instr
__device__ __forceinline__ unsigned int cvtpk(float lo, float hi) {
  unsigned int w;
  asm("v_cvt_pk_bf16_f32 %0, %1, %2" : "=v"(w) : "v"(lo), "v"(hi));
  return w;
}
// D = 2^S0
__device__ __forceinline__ float exp2v(float x) {
  float r;
  asm("v_exp_f32 %0, %1" : "=v"(r) : "v"(x));
  return r;
}

// async global->LDS, 16B per lane; LDS dest must be wave-uniform base (+ lane*16 by HW)
#define GLOAD16(g, l) __builtin_amdgcn_global_load_lds( \
    (const __attribute__((address_space(1))) unsigned int*)(g), \
    (__attribute__((address_space(3))) unsigned int*)(l), 16, 0, 0)

// ---------------- kernel 0: fp32 -> bf16 conversion (x, Wq|Wk|Wv) ----------------
__global__ __launch_bounds__(256) void conv_kernel(
    const float* __restrict__ x,
    const float* __restrict__ wq, const float* __restrict__ wk, const float* __restrict__ wv,
    unsigned short* __restrict__ xb, unsigned short* __restrict__ wb)
{
  const int NX4 = (M_ * D_) / 4;
  const int NW4 = (3 * D_ * D_) / 4;
  int stride = gridDim.x * blockDim.x;
  for (int i = blockIdx.x * blockDim.x + threadIdx.x; i < NX4 + NW4; i += stride) {
    const float4* src; unsigned short* dst; int o;
    if (i < NX4) { src = (const float4*)x; dst = xb; o = i; }
    else {
      int wi = i - NX4;
      int mat = wi >> 18;
      o = wi & 262143;
      src = (const float4*)(mat == 0 ? wq : (mat == 1 ? wk : wv));
      dst = wb + mat * (D_ * D_);
    }
    float4 v = src[o];
    us4 r; r.x = f2b(v.x); r.y = f2b(v.y); r.z = f2b(v.z); r.w = f2b(v.w);
    *(us4*)(dst + o * 4) = r;
  }
}

// ---------------- kernel 0b: Wo fp32 -> bf16 ----------------
__global__ __launch_bounds__(256) void conv_wo_kernel(
    const float* __restrict__ wo, unsigned short* __restrict__ wob)
{
  int i = blockIdx.x * 256 + threadIdx.x;       // 262144 float4s
  float4 v = ((const float4*)wo)[i];
  us4 r; r.x = f2b(v.x); r.y = f2b(v.y); r.z = f2b(v.z); r.w = f2b(v.w);
  *(us4*)(wob + i * 4) = r;
}

// ---------------- kernel 1: QKV projection GEMM (C = A * B^T) + fused RoPE -------------
// Dbuf pipeline: BK=64, stage tile t+1 (swizzled source) BEFORE computing tile t,
// ONE barrier per K-tile (vmcnt drain covered by 32 MFMA). T2: LDS chunk cc^=(row&7),
// applied inverse on the global source (rule 21), swizzled on the ds_read_b128 frags.
__global__ __launch_bounds__(256, 2) void gemm_qkv_kernel(
    const unsigned short* __restrict__ xb,
    const unsigned short* __restrict__ wb,
    const float* __restrict__ cs,        // [2048][32][2] cos/sin
    const int* __restrict__ pos,
    unsigned short* __restrict__ qb,
    unsigned short* __restrict__ kb,
    unsigned short* __restrict__ vtb)
{
  __shared__ unsigned short As[2][128 * 64];   // 32 KB
  __shared__ unsigned short Bs[2][128 * 64];   // 32 KB
  const int tid  = threadIdx.x;
  const int lane = tid & 63;
  const int wid  = tid >> 6;
  const int wm = wid >> 1, wn = wid & 1;
  const int m0 = blockIdx.x * 128;
  const int n0 = blockIdx.y * 128;          // 0..3071
  const int l15 = lane & 15, l4 = lane >> 4;
  const int swz7 = l15 & 7;                 // frag-read swizzle (row&7 == l15&7)

  // staging geometry: 1024 chunks of 16B per matrix per tile; 4 chunks/thread
  int srow[4], sgcc[4], slds[4];
  #pragma unroll
  for (int j = 0; j < 4; ++j) {
    int c = tid + j * 256;                  // chunk id 0..1023
    srow[j] = c >> 3;                       // row 0..127
    int cc  = c & 7;
    sgcc[j] = cc ^ (srow[j] & 7);           // inverse-swizzled global col-chunk
    slds[j] = (wid * 64 + j * 256) * 8;     // wave-uniform LDS base (shorts)
  }

  f32x4 acc[4][4] = {};

  // prologue: stage tile 0 -> buf 0
  #pragma unroll
  for (int j = 0; j < 4; ++j) {
    GLOAD16(xb + (m0 + srow[j]) * D_ + sgcc[j] * 8, &As[0][slds[j]]);
    GLOAD16(wb + (n0 + srow[j]) * D_ + sgcc[j] * 8, &Bs[0][slds[j]]);
  }
  __syncthreads();

  for (int t = 0; t < 16; ++t) {
    const int cur = t & 1, nxt = cur ^ 1;
    if (t < 15) {                           // stage-early: issue next tile under compute
      const int kcol = (t + 1) * 64;
      #pragma unroll
      for (int j = 0; j < 4; ++j) {
        GLOAD16(xb + (m0 + srow[j]) * D_ + kcol + sgcc[j] * 8, &As[nxt][slds[j]]);
        GLOAD16(wb + (n0 + srow[j]) * D_ + kcol + sgcc[j] * 8, &Bs[nxt][slds[j]]);
      }
    }
    const unsigned short* Ab = &As[cur][0];
    const unsigned short* Bb = &Bs[cur][0];
    #pragma unroll
    for (int ks = 0; ks < 2; ++ks) {
      const int cc = (ks * 4 + l4) ^ swz7;  // swizzled chunk within row
      short8 af[4], bfr[4];
      #pragma unroll
      for (int mi = 0; mi < 4; ++mi) af[mi]  = *(const short8*)&Ab[(wm*64 + mi*16 + l15)*64 + cc*8];
      #pragma unroll
      for (int ni = 0; ni < 4; ++ni) bfr[ni] = *(const short8*)&Bb[(wn*64 + ni*16 + l15)*64 + cc*8];
      __builtin_amdgcn_s_setprio(1);
      #pragma unroll
      for (int mi = 0; mi < 4; ++mi)
        #pragma unroll
        for (int ni = 0; ni < 4; ++ni)
          acc[mi][ni] = __builtin_amdgcn_mfma_f32_16x16x32_bf16(af[mi], bfr[ni], acc[mi][ni], 0, 0, 0);
      __builtin_amdgcn_s_setprio(0);
    }
    __syncthreads();                        // drains vmcnt (next tile landed) + joins
  }

  const int bidx = m0 >> 11;
  const int sbase = (m0 & 2047) + wm * 64;

  if (n0 < 2048) {
    // ---- q or k block: fused RoPE, [b][h][s][d] scatter ----
    unsigned short* dst = (n0 < 1024) ? qb : kb;
    const int nn0 = n0 & 1023;
    const float2* cs2 = (const float2*)cs;
    const float sg = (l15 & 1) ? 1.0f : -1.0f;
    #pragma unroll
    for (int mi = 0; mi < 4; ++mi)
      #pragma unroll
      for (int j = 0; j < 4; ++j) {
        int s = sbase + mi*16 + l4*4 + j;
        int p = pos[s];
        #pragma unroll
        for (int ni = 0; ni < 4; ++ni) {
          int col = nn0 + wn*64 + ni*16 + l15;
          int h = col >> 6, dd = col & 63;
          float val = acc[mi][ni][j];
          float par = __shfl_xor(val, 1);
          float2 cv = cs2[p*32 + (dd >> 1)];
          float r = fmaf(cv.x, val, sg * cv.y * par);
          dst[((bidx*H_ + h)*S_ + s)*DK_ + dd] = f2b(r);
        }
      }
  } else {
    // ---- v block: transposed scatter [b][h][d][s]; 8B packed stores ----
    const int nn0 = n0 & 1023;
    const int hB = (nn0 + wn*64) >> 6;
    #pragma unroll
    for (int mi = 0; mi < 4; ++mi) {
      int s4 = sbase + mi*16 + l4*4;
      #pragma unroll
      for (int ni = 0; ni < 4; ++ni) {
        int dd = ni*16 + l15;
        uint2 w;
        w.x = cvtpk(acc[mi][ni][0], acc[mi][ni][1]);
        w.y = cvtpk(acc[mi][ni][2], acc[mi][ni][3]);
        *(uint2*)(vtb + ((bidx*H_ + hB)*DK_ + dd)*S_ + s4) = w;
      }
    }
  }
}

// ---------------- kernel 3: causal flash attention v4 (unchanged from round 5) ---------
__global__ __launch_bounds__(256, 4) void attn_kernel(
    const unsigned short* __restrict__ qb,
    const unsigned short* __restrict__ kb,
    const unsigned short* __restrict__ vtb,
    unsigned short* __restrict__ ao)
{
  __shared__ unsigned short Ks[64][72];        // [key][dim]
  __shared__ unsigned short Vs[64][72];        // [dim][key]
  __shared__ unsigned short Ps[4][16][72];     // per-wave P relayout (y-groups reuse it)
  const int tid = threadIdx.x, lane = tid & 63, wid = tid >> 6;
  const int l15 = lane & 15, l4 = lane >> 4;

  const int id  = blockIdx.x;                  // 0..1023
  const int xcd = id & 7, jj2 = id >> 3;       // jj2: 0..127
  const int bh  = xcd * 8 + (jj2 & 7);         // 8 consecutive heads per XCD
  const int qt  = 15 - (jj2 >> 3);             // heavy tiles first
  const int q0  = qt * 128;
  const int nkt = 2 * qt + 2;

  const unsigned short* qp = qb  + bh * S_ * DK_;
  const unsigned short* kp = kb  + bh * S_ * DK_;
  const unsigned short* vp = vtb + bh * DK_ * S_;
  const int bidx = bh >> 4, h = bh & 15;

  const float QSC = 0.18033688f;               // (1/8)*log2(e)
  short8 qf[2][2];
  #pragma unroll
  for (int y = 0; y < 2; ++y)
    #pragma unroll
    for (int kbk = 0; kbk < 2; ++kbk) {
      short8 raw = *(const short8*)(qp + (q0 + y*64 + wid*16 + l15)*DK_ + kbk*32 + l4*8);
      #pragma unroll
      for (int i = 0; i < 8; ++i) {
        float f = b2f((unsigned short)raw[i]) * QSC;
        raw[i] = (short)f2b(f);
      }
      qf[y][kbk] = raw;
    }

  f32x4 oacc[2][4] = {};
  float mrun[2] = {-1e30f, -1e30f}, lrun[2] = {0.0f, 0.0f};

  short8 kv[2], vv[2];
  #pragma unroll
  for (int jj = 0; jj < 2; ++jj) {             // prologue: tile 0
    int c = tid + jj * 256;
    int r = c >> 3, col = (c & 7) * 8;
    kv[jj] = *(const short8*)(kp + r*DK_ + col);
    vv[jj] = *(const short8*)(vp + r*S_ + col);
  }

  for (int kt = 0; kt < nkt; ++kt) {
    __syncthreads();
    #pragma unroll
    for (int jj = 0; jj < 2; ++jj) {
      int c = tid + jj * 256;
      int r = c >> 3, col = (c & 7) * 8;
      *(short8*)&Ks[r][col] = kv[jj];
      *(short8*)&Vs[r][col] = vv[jj];
    }
    __syncthreads();

    if (kt + 1 < nkt) {                        // T14: prefetch next tile under compute
      #pragma unroll
      for (int jj = 0; jj < 2; ++jj) {
        int c = tid + jj * 256;
        int r = c >> 3, col = (c & 7) * 8;
        kv[jj] = *(const short8*)(kp + ((kt+1)*64 + r)*DK_ + col);
        vv[jj] = *(const short8*)(vp + r*S_ + (kt+1)*64 + col);
      }
    }

    #pragma unroll
    for (int y = 0; y < 2; ++y) {
      if (kt > 2*qt + y) continue;

      f32x4 sc[4];
      __builtin_amdgcn_s_setprio(1);
      #pragma unroll
      for (int nb = 0; nb < 4; ++nb) {
        short8 k0 = *(const short8*)&Ks[nb*16 + l15][l4*8];
        short8 k1 = *(const short8*)&Ks[nb*16 + l15][32 + l4*8];
        f32x4 z = {};
        z = __builtin_amdgcn_mfma_f32_16x16x32_bf16(k0, qf[y][0], z, 0, 0, 0);
        z = __builtin_amdgcn_mfma_f32_16x16x32_bf16(k1, qf[y][1], z, 0, 0, 0);
        sc[nb] = z;
      }
      __builtin_amdgcn_s_setprio(0);

      if (kt == 2*qt + y) {
        const int qg = q0 + y*64 + wid*16 + l15;
        #pragma unroll
        for (int nb = 0; nb < 4; ++nb)
          #pragma unroll
          for (int j = 0; j < 4; ++j) {
            int kg = kt*64 + nb*16 + l4*4 + j;
            if (kg > qg) sc[nb][j] = -1e30f;
          }
      }

      float tm = sc[0][0];
      #pragma unroll
      for (int nb = 0; nb < 4; ++nb)
        #pragma unroll
        for (int j = 0; j < 4; ++j) tm = fmaxf(tm, sc[nb][j]);
      tm = fmaxf(tm, __shfl_xor(tm, 16));
      tm = fmaxf(tm, __shfl_xor(tm, 32));
      if (!__all(tm - mrun[y] <= 8.0f)) {
        float mnew = fmaxf(mrun[y], tm);
        float corr = exp2v(mrun[y] - mnew);
        mrun[y] = mnew;
        lrun[y] *= corr;
        #pragma unroll
        for (int j = 0; j < 4; ++j) {
          float cj = __shfl(corr, l4*4 + j);
          #pragma unroll
          for (int nb = 0; nb < 4; ++nb) oacc[y][nb][j] *= cj;
        }
      }
      float rs = 0.0f;
      #pragma unroll
      for (int nb = 0; nb < 4; ++nb)
        #pragma unroll
        for (int j = 0; j < 4; ++j) {
          float p = exp2v(sc[nb][j] - mrun[y]);
          sc[nb][j] = p;
          rs += p;
        }
      rs += __shfl_xor(rs, 16);
      rs += __shfl_xor(rs, 32);
      lrun[y] += rs;

      #pragma unroll
      for (int nb = 0; nb < 4; ++nb) {
        uint2 w;
        w.x = cvtpk(sc[nb][0], sc[nb][1]);
        w.y = cvtpk(sc[nb][2], sc[nb][3]);
        *(uint2*)&Ps[wid][l15][nb*16 + l4*4] = w;
      }
      asm volatile("s_waitcnt lgkmcnt(0)" ::: "memory");
      short8 pa0 = *(const short8*)&Ps[wid][l15][l4*8];
      short8 pa1 = *(const short8*)&Ps[wid][l15][32 + l4*8];

      __builtin_amdgcn_s_setprio(1);
      #pragma unroll
      for (int nb = 0; nb < 4; ++nb) {
        short8 v0 = *(const short8*)&Vs[nb*16 + l15][l4*8];
        short8 v1 = *(const short8*)&Vs[nb*16 + l15][32 + l4*8];
        oacc[y][nb] = __builtin_amdgcn_mfma_f32_16x16x32_bf16(pa0, v0, oacc[y][nb], 0, 0, 0);
        oacc[y][nb] = __builtin_amdgcn_mfma_f32_16x16x32_bf16(pa1, v1, oacc[y][nb], 0, 0, 0);
      }
      __builtin_amdgcn_s_setprio(0);
    }
  }

  #pragma unroll
  for (int y = 0; y < 2; ++y)
    #pragma unroll
    for (int j = 0; j < 4; ++j) {
      float lj = __shfl(lrun[y], l4*4 + j);
      float inv = 1.0f / lj;
      int row = q0 + y*64 + wid*16 + l4*4 + j;
      #pragma unroll
      for (int nb = 0; nb < 4; ++nb) {
        int dim = nb*16 + l15;
        ao[((bidx*S_ + row)*H_ + h)*DK_ + dim] = f2b(oacc[y][nb][j] * inv);
      }
    }
}

// ---------------- kernel 4: output projection (C = A * Wo^T), fp32 out -----------------
// Same dbuf/BK=64/swizzle structure as gemm_qkv.
__global__ __launch_bounds__(256, 2) void gemm_out_kernel(
    const unsigned short* __restrict__ ao,
    const unsigned short* __restrict__ wob,
    float* __restrict__ out)
{
  __shared__ unsigned short As[2][128 * 64];
  __shared__ unsigned short Bs[2][128 * 64];
  const int tid = threadIdx.x, lane = tid & 63, wid = tid >> 6;
  const int wm = wid >> 1, wn = wid & 1;
  const int m0 = blockIdx.x * 128, n0 = blockIdx.y * 128;
  const int l15 = lane & 15, l4 = lane >> 4;
  const int swz7 = l15 & 7;

  int srow[4], sgcc[4], slds[4];
  #pragma unroll
  for (int j = 0; j < 4; ++j) {
    int c = tid + j * 256;
    srow[j] = c >> 3;
    int cc  = c & 7;
    sgcc[j] = cc ^ (srow[j] & 7);
    slds[j] = (wid * 64 + j * 256) * 8;
  }

  f32x4 acc[4][4] = {};

  #pragma unroll
  for (int j = 0; j < 4; ++j) {
    GLOAD16(ao  + (m0 + srow[j]) * D_ + sgcc[j] * 8, &As[0][slds[j]]);
    GLOAD16(wob + (n0 + srow[j]) * D_ + sgcc[j] * 8, &Bs[0][slds[j]]);
  }
  __syncthreads();

  for (int t = 0; t < 16; ++t) {
    const int cur = t & 1, nxt = cur ^ 1;
    if (t < 15) {
      const int kcol = (t + 1) * 64;
      #pragma unroll
      for (int j = 0; j < 4; ++j) {
        GLOAD16(ao  + (m0 + srow[j]) * D_ + kcol + sgcc[j] * 8, &As[nxt][slds[j]]);
        GLOAD16(wob + (n0 + srow[j]) * D_ + kcol + sgcc[j] * 8, &Bs[nxt][slds[j]]);
      }
    }
    const unsigned short* Ab = &As[cur][0];
    const unsigned short* Bb = &Bs[cur][0];
    #pragma unroll
    for (int ks = 0; ks < 2; ++ks) {
      const int cc = (ks * 4 + l4) ^ swz7;
      short8 af[4], bfr[4];
      #pragma unroll
      for (int mi = 0; mi < 4; ++mi) af[mi]  = *(const short8*)&Ab[(wm*64 + mi*16 + l15)*64 + cc*8];
      #pragma unroll
      for (int ni = 0; ni < 4; ++ni) bfr[ni] = *(const short8*)&Bb[(wn*64 + ni*16 + l15)*64 + cc*8];
      __builtin_amdgcn_s_setprio(1);
      #pragma unroll
      for (int mi = 0; mi < 4; ++mi)
        #pragma unroll
        for (int ni = 0; ni < 4; ++ni)
          acc[mi][ni] = __builtin_amdgcn_mfma_f32_16x16x32_bf16(af[mi], bfr[ni], acc[mi][ni], 0, 0, 0);
      __builtin_amdgcn_s_setprio(0);
    }
    __syncthreads();
  }

  #pragma unroll
  for (int mi = 0; mi < 4; ++mi)
    #pragma unroll
    for (int ni = 0; ni < 4; ++ni)
      #pragma unroll
      for (int j = 0; j < 4; ++j) {
        int row = m0 + wm*64 + mi*16 + l4*4 + j;
        int col = n0 + wn*64 + ni*16 + l15;
        out[row * D_ + col] = acc[mi][ni][j];
      }
}

// ---------------- launcher ----------------
extern "C" void kernel_launch(void* const* d_in, const int* in_sizes, int n_in,
                              void* d_out, int out_size, void* d_ws, size_t ws_size,
                              hipStream_t stream)
{
  const float* x  = (const float*)d_in[0];
  const float* wq = (const float*)d_in[1];
  const float* wk = (const float*)d_in[2];
  const float* wv = (const float*)d_in[3];
  const float* wo = (const float*)d_in[4];
  const float* cs = (const float*)d_in[5];
  const int*  pos = (const int*)d_in[6];
  float* out = (float*)d_out;

  unsigned short* xb = (unsigned short*)d_out;   // d_out as scratch until final GEMM
  unsigned short* wb = xb + M_ * D_;

  unsigned short* qb  = (unsigned short*)d_ws;
  unsigned short* kbf = qb  + M_ * D_;
  unsigned short* vtb = kbf + M_ * D_;
  unsigned short* aob = vtb + M_ * D_;
  unsigned short* wob = qb;                      // dead q region after attn

  conv_kernel<<<dim3(2048), dim3(256), 0, stream>>>(x, wq, wk, wv, xb, wb);
  gemm_qkv_kernel<<<dim3(64, 24), dim3(256), 0, stream>>>(xb, wb, cs, pos, qb, kbf, vtb);
  attn_kernel<<<dim3(1024), dim3(256), 0, stream>>>(qb, kbf, vtb, aob);
  conv_wo_kernel<<<dim3(1024), dim3(256), 0, stream>>>(wo, wob);
  gemm_out_kernel<<<dim3(64, 8), dim3(256), 0, stream>>>(aob, wob, out);

  (void)in_sizes; (void)n_in; (void)out_size; (void)ws_size;
}